// Round 1
// baseline (6681.930 us; speedup 1.0000x reference)
//
#include <hip/hip_runtime.h>
#include <hip/hip_bf16.h>

#define DEVFN __device__ __forceinline__

namespace {

constexpr int NN = 50000;   // nodes
constexpr int NE = 600000;  // edges
constexpr int H  = 128;
constexpr float LN_EPS = 1e-6f;

DEVFN float bf2f(unsigned int u) { return __uint_as_float(u << 16); }

DEVFN unsigned short f2bf(float f) {
  unsigned int x = __float_as_uint(f);
  x += 0x7fffu + ((x >> 16) & 1u);
  return (unsigned short)(x >> 16);
}

// acc[8][4] += xs_tile(8 rows x K) @ W(K x 128) restricted to cols c0..c0+3.
// xsrow points at row rbase of the LDS tile (pitch floats per row, %4==0).
DEVFN void mm_block(const float* xsrow, int pitch, int K,
                    const float* __restrict__ W, int c0, float (&acc)[8][4]) {
  for (int k = 0; k < K; k += 4) {
    float4 w0 = *(const float4*)(W + (size_t)(k + 0) * H + c0);
    float4 w1 = *(const float4*)(W + (size_t)(k + 1) * H + c0);
    float4 w2 = *(const float4*)(W + (size_t)(k + 2) * H + c0);
    float4 w3 = *(const float4*)(W + (size_t)(k + 3) * H + c0);
#pragma unroll
    for (int r = 0; r < 8; ++r) {
      float4 a = *(const float4*)(xsrow + r * pitch + k);
      acc[r][0] += a.x * w0.x; acc[r][0] += a.y * w1.x; acc[r][0] += a.z * w2.x; acc[r][0] += a.w * w3.x;
      acc[r][1] += a.x * w0.y; acc[r][1] += a.y * w1.y; acc[r][1] += a.z * w2.y; acc[r][1] += a.w * w3.y;
      acc[r][2] += a.x * w0.z; acc[r][2] += a.y * w1.z; acc[r][2] += a.z * w2.z; acc[r][2] += a.w * w3.z;
      acc[r][3] += a.x * w0.w; acc[r][3] += a.y * w1.w; acc[r][3] += a.z * w2.w; acc[r][3] += a.w * w3.w;
    }
  }
}

// ---------------- encoders (2-layer MLP, ReLU between) ----------------
template <int K_IN, bool OUT_BF16>
__global__ __launch_bounds__(128) void encoder_kernel(
    const float* __restrict__ x, const float* __restrict__ W0,
    const float* __restrict__ b0, const float* __restrict__ W1,
    const float* __restrict__ b1, void* __restrict__ outp, int R) {
  constexpr int PIN = K_IN + 4;
  __shared__ float xs[32 * PIN];
  __shared__ float hs[32 * 132];
  const int t = threadIdx.x;
  const int r0 = blockIdx.x * 32;

  const int nvec = 32 * K_IN / 4;
  for (int i = t; i < nvec; i += 128) {
    int rr = i / (K_IN / 4);
    int kk = (i % (K_IN / 4)) * 4;
    int row = r0 + rr;
    float4 v = make_float4(0.f, 0.f, 0.f, 0.f);
    if (row < R) v = *(const float4*)&x[(size_t)row * K_IN + kk];
    *(float4*)&xs[rr * PIN + kk] = v;
  }
  __syncthreads();

  const int c0 = (t & 31) * 4;
  const int rbase = (t >> 5) * 8;
  float acc[8][4];
  {
    float4 bb = *(const float4*)&b0[c0];
#pragma unroll
    for (int r = 0; r < 8; ++r) { acc[r][0] = bb.x; acc[r][1] = bb.y; acc[r][2] = bb.z; acc[r][3] = bb.w; }
  }
  mm_block(&xs[rbase * PIN], PIN, K_IN, W0, c0, acc);
#pragma unroll
  for (int r = 0; r < 8; ++r) {
    float4 h;
    h.x = fmaxf(acc[r][0], 0.f); h.y = fmaxf(acc[r][1], 0.f);
    h.z = fmaxf(acc[r][2], 0.f); h.w = fmaxf(acc[r][3], 0.f);
    *(float4*)&hs[(rbase + r) * 132 + c0] = h;
  }
  __syncthreads();
  {
    float4 bb = *(const float4*)&b1[c0];
#pragma unroll
    for (int r = 0; r < 8; ++r) { acc[r][0] = bb.x; acc[r][1] = bb.y; acc[r][2] = bb.z; acc[r][3] = bb.w; }
  }
  mm_block(&hs[rbase * 132], 132, H, W1, c0, acc);
#pragma unroll
  for (int r = 0; r < 8; ++r) {
    int row = r0 + rbase + r;
    if (row >= R) continue;
    if constexpr (OUT_BF16) {
      unsigned short* o = (unsigned short*)outp + (size_t)row * H + c0;
      ushort4 pk;
      pk.x = f2bf(acc[r][0]); pk.y = f2bf(acc[r][1]);
      pk.z = f2bf(acc[r][2]); pk.w = f2bf(acc[r][3]);
      *(ushort4*)o = pk;
    } else {
      float* o = (float*)outp + (size_t)row * H + c0;
      *(float4*)o = make_float4(acc[r][0], acc[r][1], acc[r][2], acc[r][3]);
    }
  }
}

// ---------------- messages: concat(n[send], e) @ W_msg, scatter-add ----------------
__global__ __launch_bounds__(128) void msg_kernel(
    const float* __restrict__ n, const unsigned short* __restrict__ e16,
    const int* __restrict__ senders, const int* __restrict__ receivers,
    const float* __restrict__ Wmsg, float* __restrict__ agg) {
  __shared__ float xs[32 * 260];
  __shared__ int sidx[32];
  __shared__ int ridx[32];
  const int t = threadIdx.x;
  const int e0 = blockIdx.x * 32;  // NE % 32 == 0, no tail
  if (t < 32) sidx[t] = senders[e0 + t];
  else if (t < 64) ridx[t - 32] = receivers[e0 + t - 32];
  __syncthreads();

  {
    const int r = t & 31, q = t >> 5;
    const float* src = &n[(size_t)sidx[r] * H + q * 32];
#pragma unroll
    for (int j = 0; j < 8; ++j) {
      *(float4*)&xs[r * 260 + q * 32 + j * 4] = *(const float4*)&src[j * 4];
    }
    const unsigned short* es = &e16[(size_t)(e0 + r) * H + q * 32];
#pragma unroll
    for (int j = 0; j < 4; ++j) {
      uint4 v = *(const uint4*)&es[j * 8];
      float* dst = &xs[r * 260 + 128 + q * 32 + j * 8];
      dst[0] = bf2f(v.x & 0xffffu); dst[1] = bf2f(v.x >> 16);
      dst[2] = bf2f(v.y & 0xffffu); dst[3] = bf2f(v.y >> 16);
      dst[4] = bf2f(v.z & 0xffffu); dst[5] = bf2f(v.z >> 16);
      dst[6] = bf2f(v.w & 0xffffu); dst[7] = bf2f(v.w >> 16);
    }
  }
  __syncthreads();

  const int c0 = (t & 31) * 4;
  const int rbase = (t >> 5) * 8;
  float acc[8][4];
#pragma unroll
  for (int r = 0; r < 8; ++r) { acc[r][0] = 0.f; acc[r][1] = 0.f; acc[r][2] = 0.f; acc[r][3] = 0.f; }
  mm_block(&xs[rbase * 260], 260, 256, Wmsg, c0, acc);

#pragma unroll
  for (int r = 0; r < 8; ++r) {
    int node = ridx[rbase + r];
    float* dst = &agg[(size_t)node * H + c0];
    atomicAdd(dst + 0, acc[r][0]);
    atomicAdd(dst + 1, acc[r][1]);
    atomicAdd(dst + 2, acc[r][2]);
    atomicAdd(dst + 3, acc[r][3]);
  }
}

// ---------------- node update: MLP(concat(n,agg)) + n@W_node, LayerNorm ----------------
__global__ __launch_bounds__(128) void node_update_kernel(
    const float* __restrict__ n, const float* __restrict__ agg,
    const float* __restrict__ W0, const float* __restrict__ b0,
    const float* __restrict__ W1, const float* __restrict__ b1,
    const float* __restrict__ Wn, const float* __restrict__ ln_g,
    const float* __restrict__ ln_b, float* __restrict__ nout) {
  __shared__ float xs[32 * 260];
  __shared__ float hs[32 * 132];
  const int t = threadIdx.x;
  const int r0 = blockIdx.x * 32;
  {
    const int r = t & 31, q = t >> 5;
    int row = r0 + r;
    if (row >= NN) row = NN - 1;  // clamp; stores guarded later
    const float* srcn = &n[(size_t)row * H + q * 32];
    const float* srca = &agg[(size_t)row * H + q * 32];
#pragma unroll
    for (int j = 0; j < 8; ++j)
      *(float4*)&xs[r * 260 + q * 32 + j * 4] = *(const float4*)&srcn[j * 4];
#pragma unroll
    for (int j = 0; j < 8; ++j)
      *(float4*)&xs[r * 260 + 128 + q * 32 + j * 4] = *(const float4*)&srca[j * 4];
  }
  __syncthreads();

  const int c0 = (t & 31) * 4;
  const int rbase = (t >> 5) * 8;
  float acc[8][4];
  {
    float4 bb = *(const float4*)&b0[c0];
#pragma unroll
    for (int r = 0; r < 8; ++r) { acc[r][0] = bb.x; acc[r][1] = bb.y; acc[r][2] = bb.z; acc[r][3] = bb.w; }
  }
  mm_block(&xs[rbase * 260], 260, 256, W0, c0, acc);
#pragma unroll
  for (int r = 0; r < 8; ++r) {
    float4 h;
    h.x = fmaxf(acc[r][0], 0.f); h.y = fmaxf(acc[r][1], 0.f);
    h.z = fmaxf(acc[r][2], 0.f); h.w = fmaxf(acc[r][3], 0.f);
    *(float4*)&hs[(rbase + r) * 132 + c0] = h;
  }
  __syncthreads();
  {
    float4 bb = *(const float4*)&b1[c0];
#pragma unroll
    for (int r = 0; r < 8; ++r) { acc[r][0] = bb.x; acc[r][1] = bb.y; acc[r][2] = bb.z; acc[r][3] = bb.w; }
  }
  mm_block(&hs[rbase * 132], 132, H, W1, c0, acc);      // h1 @ W1 + b1
  mm_block(&xs[rbase * 260], 260, H, Wn, c0, acc);      // + n @ W_node (first 128 cols of xs)

  const float4 g4 = *(const float4*)&ln_g[c0];
  const float4 bb4 = *(const float4*)&ln_b[c0];
#pragma unroll
  for (int r = 0; r < 8; ++r) {
    float s1 = acc[r][0] + acc[r][1] + acc[r][2] + acc[r][3];
    float s2 = acc[r][0] * acc[r][0] + acc[r][1] * acc[r][1] +
               acc[r][2] * acc[r][2] + acc[r][3] * acc[r][3];
#pragma unroll
    for (int m = 16; m >= 1; m >>= 1) {
      s1 += __shfl_xor(s1, m);
      s2 += __shfl_xor(s2, m);
    }
    float mu = s1 * (1.f / 128.f);
    float var = s2 * (1.f / 128.f) - mu * mu;
    float rs = rsqrtf(var + LN_EPS);
    int row = r0 + rbase + r;
    if (row < NN) {
      float4 o;
      o.x = (acc[r][0] - mu) * rs * g4.x + bb4.x;
      o.y = (acc[r][1] - mu) * rs * g4.y + bb4.y;
      o.z = (acc[r][2] - mu) * rs * g4.z + bb4.z;
      o.w = (acc[r][3] - mu) * rs * g4.w + bb4.w;
      *(float4*)&nout[(size_t)row * H + c0] = o;
    }
  }
}

// ---------------- decoder: relu(n@W0+b0) @ W1 + b1 -> [N,2] ----------------
__global__ __launch_bounds__(128) void decode_kernel(
    const float* __restrict__ n, const float* __restrict__ W0,
    const float* __restrict__ b0, const float* __restrict__ W1,
    const float* __restrict__ b1, float* __restrict__ out) {
  __shared__ float xs[32 * 132];
  __shared__ float hs[32 * 132];
  const int t = threadIdx.x;
  const int r0 = blockIdx.x * 32;
  {
    const int r = t & 31, q = t >> 5;
    int row = r0 + r;
    if (row >= NN) row = NN - 1;
    const float* src = &n[(size_t)row * H + q * 32];
#pragma unroll
    for (int j = 0; j < 8; ++j)
      *(float4*)&xs[r * 132 + q * 32 + j * 4] = *(const float4*)&src[j * 4];
  }
  __syncthreads();
  const int c0 = (t & 31) * 4;
  const int rbase = (t >> 5) * 8;
  float acc[8][4];
  {
    float4 bb = *(const float4*)&b0[c0];
#pragma unroll
    for (int r = 0; r < 8; ++r) { acc[r][0] = bb.x; acc[r][1] = bb.y; acc[r][2] = bb.z; acc[r][3] = bb.w; }
  }
  mm_block(&xs[rbase * 132], 132, H, W0, c0, acc);
#pragma unroll
  for (int r = 0; r < 8; ++r) {
    float4 h;
    h.x = fmaxf(acc[r][0], 0.f); h.y = fmaxf(acc[r][1], 0.f);
    h.z = fmaxf(acc[r][2], 0.f); h.w = fmaxf(acc[r][3], 0.f);
    *(float4*)&hs[(rbase + r) * 132 + c0] = h;
  }
  __syncthreads();
  if (t < 64) {
    int r = t >> 1, c = t & 1;
    float s = b1[c];
    for (int k = 0; k < H; ++k) s += hs[r * 132 + k] * W1[k * 2 + c];
    int row = r0 + r;
    if (row < NN) out[(size_t)row * 2 + c] = s;
  }
}

__global__ __launch_bounds__(256) void zero_kernel(float4* __restrict__ p, int n4) {
  int i = blockIdx.x * 256 + threadIdx.x;
  if (i < n4) p[i] = make_float4(0.f, 0.f, 0.f, 0.f);
}

}  // namespace

extern "C" void kernel_launch(void* const* d_in, const int* in_sizes, int n_in,
                              void* d_out, int out_size, void* d_ws, size_t ws_size,
                              hipStream_t stream) {
  const float* nodes     = (const float*)d_in[0];
  const float* edges     = (const float*)d_in[1];
  const int*   senders   = (const int*)d_in[2];
  const int*   receivers = (const int*)d_in[3];
  const float* enc_n_W0 = (const float*)d_in[4];
  const float* enc_n_b0 = (const float*)d_in[5];
  const float* enc_n_W1 = (const float*)d_in[6];
  const float* enc_n_b1 = (const float*)d_in[7];
  const float* enc_e_W0 = (const float*)d_in[8];
  const float* enc_e_b0 = (const float*)d_in[9];
  const float* enc_e_W1 = (const float*)d_in[10];
  const float* enc_e_b1 = (const float*)d_in[11];
  const float* W_msg    = (const float*)d_in[12];
  const float* node_W0  = (const float*)d_in[13];
  const float* node_b0  = (const float*)d_in[14];
  const float* node_W1  = (const float*)d_in[15];
  const float* node_b1  = (const float*)d_in[16];
  const float* W_node   = (const float*)d_in[17];
  const float* ln_g     = (const float*)d_in[18];
  const float* ln_b     = (const float*)d_in[19];
  const float* dec_W0   = (const float*)d_in[20];
  const float* dec_b0   = (const float*)d_in[21];
  const float* dec_W1   = (const float*)d_in[22];
  const float* dec_b1   = (const float*)d_in[23];
  float* out = (float*)d_out;

  char* ws = (char*)d_ws;
  unsigned short* e16 = (unsigned short*)ws;                 // NE*H bf16 = 153.6 MB
  float* n0  = (float*)(ws + (size_t)NE * H * 2);            // 25.6 MB
  float* n1  = n0 + (size_t)NN * H;                          // 25.6 MB
  float* agg = n1 + (size_t)NN * H;                          // 25.6 MB

  const int nodeBlocks = (NN + 31) / 32;   // 1563
  const int edgeBlocks = NE / 32;          // 18750

  encoder_kernel<32, false><<<nodeBlocks, 128, 0, stream>>>(
      nodes, enc_n_W0, enc_n_b0, enc_n_W1, enc_n_b1, (void*)n0, NN);
  encoder_kernel<16, true><<<edgeBlocks, 128, 0, stream>>>(
      edges, enc_e_W0, enc_e_b0, enc_e_W1, enc_e_b1, (void*)e16, NE);

  float* ncur = n0;
  float* nnxt = n1;
  const int n4 = NN * H / 4;
  for (int p = 0; p < 5; ++p) {
    zero_kernel<<<(n4 + 255) / 256, 256, 0, stream>>>((float4*)agg, n4);
    msg_kernel<<<edgeBlocks, 128, 0, stream>>>(ncur, e16, senders, receivers, W_msg, agg);
    node_update_kernel<<<nodeBlocks, 128, 0, stream>>>(
        ncur, agg, node_W0, node_b0, node_W1, node_b1, W_node, ln_g, ln_b, nnxt);
    float* tmp = ncur; ncur = nnxt; nnxt = tmp;
  }

  decode_kernel<<<nodeBlocks, 128, 0, stream>>>(ncur, dec_W0, dec_b0, dec_W1, dec_b1, out);
}

// Round 2
// 1783.403 us; speedup vs baseline: 3.7467x; 3.7467x over previous
//
#include <hip/hip_runtime.h>

#define DEVFN __device__ __forceinline__

namespace {

constexpr int NN = 50000;   // nodes
constexpr int NE = 600000;  // edges
constexpr int H  = 128;
constexpr float LN_EPS = 1e-6f;

// acc[8][4] += xs_tile(8 rows x K) @ W(K x 128) restricted to cols c0..c0+3.
DEVFN void mm_block(const float* xsrow, int pitch, int K,
                    const float* __restrict__ W, int c0, float (&acc)[8][4]) {
  for (int k = 0; k < K; k += 4) {
    float4 w0 = *(const float4*)(W + (size_t)(k + 0) * H + c0);
    float4 w1 = *(const float4*)(W + (size_t)(k + 1) * H + c0);
    float4 w2 = *(const float4*)(W + (size_t)(k + 2) * H + c0);
    float4 w3 = *(const float4*)(W + (size_t)(k + 3) * H + c0);
#pragma unroll
    for (int r = 0; r < 8; ++r) {
      float4 a = *(const float4*)(xsrow + r * pitch + k);
      acc[r][0] += a.x * w0.x; acc[r][0] += a.y * w1.x; acc[r][0] += a.z * w2.x; acc[r][0] += a.w * w3.x;
      acc[r][1] += a.x * w0.y; acc[r][1] += a.y * w1.y; acc[r][1] += a.z * w2.y; acc[r][1] += a.w * w3.y;
      acc[r][2] += a.x * w0.z; acc[r][2] += a.y * w1.z; acc[r][2] += a.z * w2.z; acc[r][2] += a.w * w3.z;
      acc[r][3] += a.x * w0.w; acc[r][3] += a.y * w1.w; acc[r][3] += a.z * w2.w; acc[r][3] += a.w * w3.w;
    }
  }
}

// ---------------- node encoder (2-layer MLP, ReLU between) ----------------
template <int K_IN>
__global__ __launch_bounds__(128) void encoder_kernel(
    const float* __restrict__ x, const float* __restrict__ W0,
    const float* __restrict__ b0, const float* __restrict__ W1,
    const float* __restrict__ b1, float* __restrict__ outp, int R) {
  constexpr int PIN = K_IN + 4;
  __shared__ float xs[32 * PIN];
  __shared__ float hs[32 * 132];
  const int t = threadIdx.x;
  const int r0 = blockIdx.x * 32;

  const int nvec = 32 * K_IN / 4;
  for (int i = t; i < nvec; i += 128) {
    int rr = i / (K_IN / 4);
    int kk = (i % (K_IN / 4)) * 4;
    int row = r0 + rr;
    float4 v = make_float4(0.f, 0.f, 0.f, 0.f);
    if (row < R) v = *(const float4*)&x[(size_t)row * K_IN + kk];
    *(float4*)&xs[rr * PIN + kk] = v;
  }
  __syncthreads();

  const int c0 = (t & 31) * 4;
  const int rbase = (t >> 5) * 8;
  float acc[8][4];
  {
    float4 bb = *(const float4*)&b0[c0];
#pragma unroll
    for (int r = 0; r < 8; ++r) { acc[r][0] = bb.x; acc[r][1] = bb.y; acc[r][2] = bb.z; acc[r][3] = bb.w; }
  }
  mm_block(&xs[rbase * PIN], PIN, K_IN, W0, c0, acc);
#pragma unroll
  for (int r = 0; r < 8; ++r) {
    float4 h;
    h.x = fmaxf(acc[r][0], 0.f); h.y = fmaxf(acc[r][1], 0.f);
    h.z = fmaxf(acc[r][2], 0.f); h.w = fmaxf(acc[r][3], 0.f);
    *(float4*)&hs[(rbase + r) * 132 + c0] = h;
  }
  __syncthreads();
  {
    float4 bb = *(const float4*)&b1[c0];
#pragma unroll
    for (int r = 0; r < 8; ++r) { acc[r][0] = bb.x; acc[r][1] = bb.y; acc[r][2] = bb.z; acc[r][3] = bb.w; }
  }
  mm_block(&hs[rbase * 132], 132, H, W1, c0, acc);
#pragma unroll
  for (int r = 0; r < 8; ++r) {
    int row = r0 + rbase + r;
    if (row < R)
      *(float4*)&outp[(size_t)row * H + c0] =
          make_float4(acc[r][0], acc[r][1], acc[r][2], acc[r][3]);
  }
}

// ---------------- generic y[R,128] = x[R,128] @ W[128,128] (no bias) ----------------
__global__ __launch_bounds__(128) void linear_kernel(
    const float* __restrict__ x, const float* __restrict__ W,
    float* __restrict__ y, int R) {
  __shared__ float xs[32 * 132];
  const int t = threadIdx.x;
  const int r0 = blockIdx.x * 32;
  {
    const int r = t & 31, q = t >> 5;
    int row = r0 + r;
    if (row >= R) row = R - 1;
    const float* src = &x[(size_t)row * H + q * 32];
#pragma unroll
    for (int j = 0; j < 8; ++j)
      *(float4*)&xs[r * 132 + q * 32 + j * 4] = *(const float4*)&src[j * 4];
  }
  __syncthreads();
  const int c0 = (t & 31) * 4;
  const int rbase = (t >> 5) * 8;
  float acc[8][4];
#pragma unroll
  for (int r = 0; r < 8; ++r) { acc[r][0] = 0.f; acc[r][1] = 0.f; acc[r][2] = 0.f; acc[r][3] = 0.f; }
  mm_block(&xs[rbase * 132], 132, H, W, c0, acc);
#pragma unroll
  for (int r = 0; r < 8; ++r) {
    int row = r0 + rbase + r;
    if (row < R)
      *(float4*)&y[(size_t)row * H + c0] =
          make_float4(acc[r][0], acc[r][1], acc[r][2], acc[r][3]);
  }
}

// bc[j] = sum_k b1[k] * Wb[k*128 + j]   (tiny, 1 block)
__global__ __launch_bounds__(128) void bc_kernel(
    const float* __restrict__ b1, const float* __restrict__ Wb,
    float* __restrict__ bc) {
  int j = threadIdx.x;
  float s = 0.f;
  for (int k = 0; k < H; ++k) s += b1[k] * Wb[(size_t)k * H + j];
  bc[j] = s;
}

// ---------------- counting sort by receiver ----------------
__global__ __launch_bounds__(256) void hist_kernel(const int* __restrict__ recv,
                                                   int* __restrict__ cnt) {
  int i = blockIdx.x * 256 + threadIdx.x;
  if (i < NE) atomicAdd(&cnt[recv[i]], 1);
}

__global__ __launch_bounds__(256) void scan1_kernel(const int* __restrict__ cnt,
                                                    int* __restrict__ excl,
                                                    int* __restrict__ part) {
  __shared__ int s[256];
  int t = threadIdx.x;
  int i = blockIdx.x * 256 + t;
  int v = (i < NN) ? cnt[i] : 0;
  s[t] = v;
  __syncthreads();
  for (int off = 1; off < 256; off <<= 1) {
    int x = (t >= off) ? s[t - off] : 0;
    __syncthreads();
    s[t] += x;
    __syncthreads();
  }
  if (i < NN) excl[i] = s[t] - v;
  if (t == 255) part[blockIdx.x] = s[255];
}

__global__ __launch_bounds__(256) void scan2_kernel(int* __restrict__ part, int nb) {
  __shared__ int s[256];
  int t = threadIdx.x;
  int v = (t < nb) ? part[t] : 0;
  s[t] = v;
  __syncthreads();
  for (int off = 1; off < 256; off <<= 1) {
    int x = (t >= off) ? s[t - off] : 0;
    __syncthreads();
    s[t] += x;
    __syncthreads();
  }
  if (t < nb) part[t] = s[t] - v;
}

__global__ __launch_bounds__(256) void scan3_kernel(int* __restrict__ excl,
                                                    const int* __restrict__ part,
                                                    int* __restrict__ cursor) {
  int i = blockIdx.x * 256 + threadIdx.x;
  if (i < NN) {
    int e = excl[i] + part[i >> 8];
    excl[i] = e;
    cursor[i] = e;
  }
}

__global__ __launch_bounds__(256) void scatter_kernel(
    const int* __restrict__ senders, const int* __restrict__ recv,
    int* __restrict__ cursor, int* __restrict__ sendp,
    int* __restrict__ eperm, int* __restrict__ recvp) {
  int i = blockIdx.x * 256 + threadIdx.x;
  if (i < NE) {
    int r = recv[i];
    int pos = atomicAdd(&cursor[r], 1);
    sendp[pos] = senders[i];
    eperm[pos] = i;
    recvp[pos] = r;
  }
}

// ---------------- B[v] = segment_sum( relu(edges@W0+b0) @ Wc + bc ) ----------------
// Edges processed in receiver-sorted order; run-compressed boundary atomics.
__global__ __launch_bounds__(128) void bagg_kernel(
    const float* __restrict__ edges, const int* __restrict__ eperm,
    const int* __restrict__ recvp, const float* __restrict__ W0,
    const float* __restrict__ b0, const float* __restrict__ Wc,
    const float* __restrict__ bc, float* __restrict__ B) {
  __shared__ float xs[32 * 20];
  __shared__ float hs[32 * 132];
  __shared__ int rs[32];
  const int t = threadIdx.x;
  const int e0 = blockIdx.x * 32;  // NE % 32 == 0
  if (t < 32) rs[t] = recvp[e0 + t];
  {
    int row = t >> 2, c = (t & 3) * 4;
    int ep = eperm[e0 + row];
    *(float4*)&xs[row * 20 + c] = *(const float4*)&edges[(size_t)ep * 16 + c];
  }
  __syncthreads();
  const int c0 = (t & 31) * 4;
  const int rbase = (t >> 5) * 8;
  float acc[8][4];
  {
    float4 bb = *(const float4*)&b0[c0];
#pragma unroll
    for (int r = 0; r < 8; ++r) { acc[r][0] = bb.x; acc[r][1] = bb.y; acc[r][2] = bb.z; acc[r][3] = bb.w; }
  }
  mm_block(&xs[rbase * 20], 20, 16, W0, c0, acc);
#pragma unroll
  for (int r = 0; r < 8; ++r) {
    float4 h;
    h.x = fmaxf(acc[r][0], 0.f); h.y = fmaxf(acc[r][1], 0.f);
    h.z = fmaxf(acc[r][2], 0.f); h.w = fmaxf(acc[r][3], 0.f);
    *(float4*)&hs[(rbase + r) * 132 + c0] = h;
  }
  __syncthreads();
  {
    float4 bb = *(const float4*)&bc[c0];
#pragma unroll
    for (int r = 0; r < 8; ++r) { acc[r][0] = bb.x; acc[r][1] = bb.y; acc[r][2] = bb.z; acc[r][3] = bb.w; }
  }
  mm_block(&hs[rbase * 132], 132, H, Wc, c0, acc);

  // run-compressed segment reduce over this thread's 8 sorted rows
  int cur = rs[rbase];
  float r0 = acc[0][0], r1 = acc[0][1], r2 = acc[0][2], r3 = acc[0][3];
#pragma unroll
  for (int r = 1; r < 8; ++r) {
    int nd = rs[rbase + r];
    if (nd != cur) {
      float* dst = &B[(size_t)cur * H + c0];
      atomicAdd(dst + 0, r0); atomicAdd(dst + 1, r1);
      atomicAdd(dst + 2, r2); atomicAdd(dst + 3, r3);
      cur = nd;
      r0 = acc[r][0]; r1 = acc[r][1]; r2 = acc[r][2]; r3 = acc[r][3];
    } else {
      r0 += acc[r][0]; r1 += acc[r][1]; r2 += acc[r][2]; r3 += acc[r][3];
    }
  }
  float* dst = &B[(size_t)cur * H + c0];
  atomicAdd(dst + 0, r0); atomicAdd(dst + 1, r1);
  atomicAdd(dst + 2, r2); atomicAdd(dst + 3, r3);
}

// ---------------- per-pass: agg[v] = B[v] + sum_{j in [start,end)} nt[sendp[j]] ----------------
__global__ __launch_bounds__(256) void agg_kernel(
    const float* __restrict__ nt, const float* __restrict__ Bv,
    const int* __restrict__ start, const int* __restrict__ endc,
    const int* __restrict__ sendp, float* __restrict__ agg) {
  const int t = threadIdx.x;
  const int v = blockIdx.x * 4 + (t >> 6);  // NN % 4 == 0
  const int c = (t & 63) * 2;
  float2 a = *(const float2*)&Bv[(size_t)v * H + c];
  int j = start[v];
  const int e = endc[v];
  for (; j + 1 < e; j += 2) {
    int s0 = sendp[j], s1 = sendp[j + 1];
    float2 x0 = *(const float2*)&nt[(size_t)s0 * H + c];
    float2 x1 = *(const float2*)&nt[(size_t)s1 * H + c];
    a.x += x0.x + x1.x;
    a.y += x0.y + x1.y;
  }
  if (j < e) {
    int s0 = sendp[j];
    float2 x0 = *(const float2*)&nt[(size_t)s0 * H + c];
    a.x += x0.x;
    a.y += x0.y;
  }
  *(float2*)&agg[(size_t)v * H + c] = a;
}

// ---------------- node update: MLP(concat(n,agg)) + n@W_node, LayerNorm ----------------
__global__ __launch_bounds__(128) void node_update_kernel(
    const float* __restrict__ n, const float* __restrict__ agg,
    const float* __restrict__ W0, const float* __restrict__ b0,
    const float* __restrict__ W1, const float* __restrict__ b1,
    const float* __restrict__ Wn, const float* __restrict__ ln_g,
    const float* __restrict__ ln_b, float* __restrict__ nout) {
  __shared__ float xs[32 * 260];
  __shared__ float hs[32 * 132];
  const int t = threadIdx.x;
  const int r0 = blockIdx.x * 32;
  {
    const int r = t & 31, q = t >> 5;
    int row = r0 + r;
    if (row >= NN) row = NN - 1;
    const float* srcn = &n[(size_t)row * H + q * 32];
    const float* srca = &agg[(size_t)row * H + q * 32];
#pragma unroll
    for (int j = 0; j < 8; ++j)
      *(float4*)&xs[r * 260 + q * 32 + j * 4] = *(const float4*)&srcn[j * 4];
#pragma unroll
    for (int j = 0; j < 8; ++j)
      *(float4*)&xs[r * 260 + 128 + q * 32 + j * 4] = *(const float4*)&srca[j * 4];
  }
  __syncthreads();

  const int c0 = (t & 31) * 4;
  const int rbase = (t >> 5) * 8;
  float acc[8][4];
  {
    float4 bb = *(const float4*)&b0[c0];
#pragma unroll
    for (int r = 0; r < 8; ++r) { acc[r][0] = bb.x; acc[r][1] = bb.y; acc[r][2] = bb.z; acc[r][3] = bb.w; }
  }
  mm_block(&xs[rbase * 260], 260, 256, W0, c0, acc);
#pragma unroll
  for (int r = 0; r < 8; ++r) {
    float4 h;
    h.x = fmaxf(acc[r][0], 0.f); h.y = fmaxf(acc[r][1], 0.f);
    h.z = fmaxf(acc[r][2], 0.f); h.w = fmaxf(acc[r][3], 0.f);
    *(float4*)&hs[(rbase + r) * 132 + c0] = h;
  }
  __syncthreads();
  {
    float4 bb = *(const float4*)&b1[c0];
#pragma unroll
    for (int r = 0; r < 8; ++r) { acc[r][0] = bb.x; acc[r][1] = bb.y; acc[r][2] = bb.z; acc[r][3] = bb.w; }
  }
  mm_block(&hs[rbase * 132], 132, H, W1, c0, acc);   // h1 @ W1 + b1
  mm_block(&xs[rbase * 260], 260, H, Wn, c0, acc);   // + n @ W_node

  const float4 g4 = *(const float4*)&ln_g[c0];
  const float4 bb4 = *(const float4*)&ln_b[c0];
#pragma unroll
  for (int r = 0; r < 8; ++r) {
    float s1 = acc[r][0] + acc[r][1] + acc[r][2] + acc[r][3];
    float s2 = acc[r][0] * acc[r][0] + acc[r][1] * acc[r][1] +
               acc[r][2] * acc[r][2] + acc[r][3] * acc[r][3];
#pragma unroll
    for (int m = 16; m >= 1; m >>= 1) {
      s1 += __shfl_xor(s1, m);
      s2 += __shfl_xor(s2, m);
    }
    float mu = s1 * (1.f / 128.f);
    float var = s2 * (1.f / 128.f) - mu * mu;
    float rs = rsqrtf(var + LN_EPS);
    int row = r0 + rbase + r;
    if (row < NN) {
      float4 o;
      o.x = (acc[r][0] - mu) * rs * g4.x + bb4.x;
      o.y = (acc[r][1] - mu) * rs * g4.y + bb4.y;
      o.z = (acc[r][2] - mu) * rs * g4.z + bb4.z;
      o.w = (acc[r][3] - mu) * rs * g4.w + bb4.w;
      *(float4*)&nout[(size_t)row * H + c0] = o;
    }
  }
}

// ---------------- decoder ----------------
__global__ __launch_bounds__(128) void decode_kernel(
    const float* __restrict__ n, const float* __restrict__ W0,
    const float* __restrict__ b0, const float* __restrict__ W1,
    const float* __restrict__ b1, float* __restrict__ out) {
  __shared__ float xs[32 * 132];
  __shared__ float hs[32 * 132];
  const int t = threadIdx.x;
  const int r0 = blockIdx.x * 32;
  {
    const int r = t & 31, q = t >> 5;
    int row = r0 + r;
    if (row >= NN) row = NN - 1;
    const float* src = &n[(size_t)row * H + q * 32];
#pragma unroll
    for (int j = 0; j < 8; ++j)
      *(float4*)&xs[r * 132 + q * 32 + j * 4] = *(const float4*)&src[j * 4];
  }
  __syncthreads();
  const int c0 = (t & 31) * 4;
  const int rbase = (t >> 5) * 8;
  float acc[8][4];
  {
    float4 bb = *(const float4*)&b0[c0];
#pragma unroll
    for (int r = 0; r < 8; ++r) { acc[r][0] = bb.x; acc[r][1] = bb.y; acc[r][2] = bb.z; acc[r][3] = bb.w; }
  }
  mm_block(&xs[rbase * 132], 132, H, W0, c0, acc);
#pragma unroll
  for (int r = 0; r < 8; ++r) {
    float4 h;
    h.x = fmaxf(acc[r][0], 0.f); h.y = fmaxf(acc[r][1], 0.f);
    h.z = fmaxf(acc[r][2], 0.f); h.w = fmaxf(acc[r][3], 0.f);
    *(float4*)&hs[(rbase + r) * 132 + c0] = h;
  }
  __syncthreads();
  if (t < 64) {
    int r = t >> 1, c = t & 1;
    float s = b1[c];
    for (int k = 0; k < H; ++k) s += hs[r * 132 + k] * W1[k * 2 + c];
    int row = r0 + r;
    if (row < NN) out[(size_t)row * 2 + c] = s;
  }
}

__global__ __launch_bounds__(256) void zero_kernel(float4* __restrict__ p, int n4) {
  int i = blockIdx.x * 256 + threadIdx.x;
  if (i < n4) p[i] = make_float4(0.f, 0.f, 0.f, 0.f);
}

}  // namespace

extern "C" void kernel_launch(void* const* d_in, const int* in_sizes, int n_in,
                              void* d_out, int out_size, void* d_ws, size_t ws_size,
                              hipStream_t stream) {
  const float* nodes     = (const float*)d_in[0];
  const float* edges     = (const float*)d_in[1];
  const int*   senders   = (const int*)d_in[2];
  const int*   receivers = (const int*)d_in[3];
  const float* enc_n_W0 = (const float*)d_in[4];
  const float* enc_n_b0 = (const float*)d_in[5];
  const float* enc_n_W1 = (const float*)d_in[6];
  const float* enc_n_b1 = (const float*)d_in[7];
  const float* enc_e_W0 = (const float*)d_in[8];
  const float* enc_e_b0 = (const float*)d_in[9];
  const float* enc_e_W1 = (const float*)d_in[10];
  const float* enc_e_b1 = (const float*)d_in[11];
  const float* W_msg    = (const float*)d_in[12];
  const float* node_W0  = (const float*)d_in[13];
  const float* node_b0  = (const float*)d_in[14];
  const float* node_W1  = (const float*)d_in[15];
  const float* node_b1  = (const float*)d_in[16];
  const float* W_node   = (const float*)d_in[17];
  const float* ln_g     = (const float*)d_in[18];
  const float* ln_b     = (const float*)d_in[19];
  const float* dec_W0   = (const float*)d_in[20];
  const float* dec_b0   = (const float*)d_in[21];
  const float* dec_W1   = (const float*)d_in[22];
  const float* dec_b1   = (const float*)d_in[23];
  float* out = (float*)d_out;

  const float* Wt = W_msg;                 // rows 0..127 of W_msg
  const float* Wb = W_msg + 128 * H;       // rows 128..255

  // workspace layout (fp32 unless noted); total ~136 MB
  float* n0   = (float*)d_ws;
  float* n1   = n0 + (size_t)NN * H;
  float* nt   = n1 + (size_t)NN * H;
  float* agg  = nt + (size_t)NN * H;
  float* B    = agg + (size_t)NN * H;
  float* Wc   = B + (size_t)NN * H;        // 128*128
  float* bc   = Wc + 128 * H;              // 128 (pad to 128)
  int* cnt    = (int*)(bc + 128);
  int* excl   = cnt + NN;
  int* cursor = excl + NN;
  int* part   = cursor + NN;               // 256
  int* sendp  = part + 256;                // NE
  int* eperm  = sendp + NE;                // NE
  int* recvp  = eperm + NE;                // NE

  const int nodeBlocks = (NN + 31) / 32;   // 1563
  const int edgeBlocks = NE / 32;          // 18750
  const int scanBlocks = (NN + 255) / 256; // 196
  const int neBlocks   = (NE + 255) / 256; // 2344

  // --- one-time per launch: sort edges by receiver, fold edge path into B ---
  zero_kernel<<<(NN / 4 + 255) / 256, 256, 0, stream>>>((float4*)cnt, NN / 4);
  zero_kernel<<<(NN * H / 4 + 255) / 256, 256, 0, stream>>>((float4*)B, NN * H / 4);
  hist_kernel<<<neBlocks, 256, 0, stream>>>(receivers, cnt);
  scan1_kernel<<<scanBlocks, 256, 0, stream>>>(cnt, excl, part);
  scan2_kernel<<<1, 256, 0, stream>>>(part, scanBlocks);
  scan3_kernel<<<scanBlocks, 256, 0, stream>>>(excl, part, cursor);
  scatter_kernel<<<neBlocks, 256, 0, stream>>>(senders, receivers, cursor, sendp, eperm, recvp);

  linear_kernel<<<4, 128, 0, stream>>>(enc_e_W1, Wb, Wc, 128);  // Wc = W1 @ Wb
  bc_kernel<<<1, 128, 0, stream>>>(enc_e_b1, Wb, bc);           // bc = b1 @ Wb
  encoder_kernel<32><<<nodeBlocks, 128, 0, stream>>>(
      nodes, enc_n_W0, enc_n_b0, enc_n_W1, enc_n_b1, n0, NN);
  bagg_kernel<<<edgeBlocks, 128, 0, stream>>>(
      edges, eperm, recvp, enc_e_W0, enc_e_b0, Wc, bc, B);

  // --- 5 weight-tied passes ---
  float* ncur = n0;
  float* nnxt = n1;
  for (int p = 0; p < 5; ++p) {
    linear_kernel<<<nodeBlocks, 128, 0, stream>>>(ncur, Wt, nt, NN);  // nt = n @ Wt
    agg_kernel<<<NN / 4, 256, 0, stream>>>(nt, B, excl, cursor, sendp, agg);
    node_update_kernel<<<nodeBlocks, 128, 0, stream>>>(
        ncur, agg, node_W0, node_b0, node_W1, node_b1, W_node, ln_g, ln_b, nnxt);
    float* tmp = ncur; ncur = nnxt; nnxt = tmp;
  }

  decode_kernel<<<nodeBlocks, 128, 0, stream>>>(ncur, dec_W0, dec_b0, dec_W1, dec_b1, out);
}

// Round 3
// 1554.120 us; speedup vs baseline: 4.2995x; 1.1475x over previous
//
#include <hip/hip_runtime.h>

#define DEVFN __device__ __forceinline__

namespace {

constexpr int NN = 50000;   // nodes
constexpr int NE = 600000;  // edges
constexpr int H  = 128;
constexpr float LN_EPS = 1e-6f;

DEVFN float bf2f(unsigned int u) { return __uint_as_float(u << 16); }

DEVFN unsigned short f2bf(float f) {
  unsigned int x = __float_as_uint(f);
  x += 0x7fffu + ((x >> 16) & 1u);
  return (unsigned short)(x >> 16);
}

// acc[8][4] += xs_tile(8 rows x K) @ W(K x 128) restricted to cols c0..c0+3.
DEVFN void mm_block(const float* xsrow, int pitch, int K,
                    const float* __restrict__ W, int c0, float (&acc)[8][4]) {
  for (int k = 0; k < K; k += 4) {
    float4 w0 = *(const float4*)(W + (size_t)(k + 0) * H + c0);
    float4 w1 = *(const float4*)(W + (size_t)(k + 1) * H + c0);
    float4 w2 = *(const float4*)(W + (size_t)(k + 2) * H + c0);
    float4 w3 = *(const float4*)(W + (size_t)(k + 3) * H + c0);
#pragma unroll
    for (int r = 0; r < 8; ++r) {
      float4 a = *(const float4*)(xsrow + r * pitch + k);
      acc[r][0] += a.x * w0.x; acc[r][0] += a.y * w1.x; acc[r][0] += a.z * w2.x; acc[r][0] += a.w * w3.x;
      acc[r][1] += a.x * w0.y; acc[r][1] += a.y * w1.y; acc[r][1] += a.z * w2.y; acc[r][1] += a.w * w3.y;
      acc[r][2] += a.x * w0.z; acc[r][2] += a.y * w1.z; acc[r][2] += a.z * w2.z; acc[r][2] += a.w * w3.z;
      acc[r][3] += a.x * w0.w; acc[r][3] += a.y * w1.w; acc[r][3] += a.z * w2.w; acc[r][3] += a.w * w3.w;
    }
  }
}

// ---------------- node encoder (2-layer MLP, ReLU between) ----------------
template <int K_IN>
__global__ __launch_bounds__(128) void encoder_kernel(
    const float* __restrict__ x, const float* __restrict__ W0,
    const float* __restrict__ b0, const float* __restrict__ W1,
    const float* __restrict__ b1, float* __restrict__ outp, int R) {
  constexpr int PIN = K_IN + 4;
  __shared__ float xs[32 * PIN];
  __shared__ float hs[32 * 132];
  const int t = threadIdx.x;
  const int r0 = blockIdx.x * 32;

  const int nvec = 32 * K_IN / 4;
  for (int i = t; i < nvec; i += 128) {
    int rr = i / (K_IN / 4);
    int kk = (i % (K_IN / 4)) * 4;
    int row = r0 + rr;
    float4 v = make_float4(0.f, 0.f, 0.f, 0.f);
    if (row < R) v = *(const float4*)&x[(size_t)row * K_IN + kk];
    *(float4*)&xs[rr * PIN + kk] = v;
  }
  __syncthreads();

  const int c0 = (t & 31) * 4;
  const int rbase = (t >> 5) * 8;
  float acc[8][4];
  {
    float4 bb = *(const float4*)&b0[c0];
#pragma unroll
    for (int r = 0; r < 8; ++r) { acc[r][0] = bb.x; acc[r][1] = bb.y; acc[r][2] = bb.z; acc[r][3] = bb.w; }
  }
  mm_block(&xs[rbase * PIN], PIN, K_IN, W0, c0, acc);
#pragma unroll
  for (int r = 0; r < 8; ++r) {
    float4 h;
    h.x = fmaxf(acc[r][0], 0.f); h.y = fmaxf(acc[r][1], 0.f);
    h.z = fmaxf(acc[r][2], 0.f); h.w = fmaxf(acc[r][3], 0.f);
    *(float4*)&hs[(rbase + r) * 132 + c0] = h;
  }
  __syncthreads();
  {
    float4 bb = *(const float4*)&b1[c0];
#pragma unroll
    for (int r = 0; r < 8; ++r) { acc[r][0] = bb.x; acc[r][1] = bb.y; acc[r][2] = bb.z; acc[r][3] = bb.w; }
  }
  mm_block(&hs[rbase * 132], 132, H, W1, c0, acc);
#pragma unroll
  for (int r = 0; r < 8; ++r) {
    int row = r0 + rbase + r;
    if (row < R)
      *(float4*)&outp[(size_t)row * H + c0] =
          make_float4(acc[r][0], acc[r][1], acc[r][2], acc[r][3]);
  }
}

// ---------------- y[R,128] = x[R,128] @ W[128,128], optional bf16 out ----------------
template <bool OUT_BF16>
__global__ __launch_bounds__(128) void linear_kernel(
    const float* __restrict__ x, const float* __restrict__ W,
    void* __restrict__ yp, int R) {
  __shared__ float xs[32 * 132];
  const int t = threadIdx.x;
  const int r0 = blockIdx.x * 32;
  {
    const int r = t & 31, q = t >> 5;
    int row = r0 + r;
    if (row >= R) row = R - 1;
    const float* src = &x[(size_t)row * H + q * 32];
#pragma unroll
    for (int j = 0; j < 8; ++j)
      *(float4*)&xs[r * 132 + q * 32 + j * 4] = *(const float4*)&src[j * 4];
  }
  __syncthreads();
  const int c0 = (t & 31) * 4;
  const int rbase = (t >> 5) * 8;
  float acc[8][4];
#pragma unroll
  for (int r = 0; r < 8; ++r) { acc[r][0] = 0.f; acc[r][1] = 0.f; acc[r][2] = 0.f; acc[r][3] = 0.f; }
  mm_block(&xs[rbase * 132], 132, H, W, c0, acc);
#pragma unroll
  for (int r = 0; r < 8; ++r) {
    int row = r0 + rbase + r;
    if (row < R) {
      if constexpr (OUT_BF16) {
        ushort4 pk;
        pk.x = f2bf(acc[r][0]); pk.y = f2bf(acc[r][1]);
        pk.z = f2bf(acc[r][2]); pk.w = f2bf(acc[r][3]);
        *(ushort4*)((unsigned short*)yp + (size_t)row * H + c0) = pk;
      } else {
        *(float4*)((float*)yp + (size_t)row * H + c0) =
            make_float4(acc[r][0], acc[r][1], acc[r][2], acc[r][3]);
      }
    }
  }
}

// bc[j] = sum_k b1[k] * Wb[k*128 + j]   (tiny, 1 block)
__global__ __launch_bounds__(128) void bc_kernel(
    const float* __restrict__ b1, const float* __restrict__ Wb,
    float* __restrict__ bc) {
  int j = threadIdx.x;
  float s = 0.f;
  for (int k = 0; k < H; ++k) s += b1[k] * Wb[(size_t)k * H + j];
  bc[j] = s;
}

// ---------------- counting sort by receiver ----------------
__global__ __launch_bounds__(256) void hist_kernel(const int* __restrict__ recv,
                                                   int* __restrict__ cnt) {
  int i = blockIdx.x * 256 + threadIdx.x;
  if (i < NE) atomicAdd(&cnt[recv[i]], 1);
}

__global__ __launch_bounds__(256) void scan1_kernel(const int* __restrict__ cnt,
                                                    int* __restrict__ excl,
                                                    int* __restrict__ part) {
  __shared__ int s[256];
  int t = threadIdx.x;
  int i = blockIdx.x * 256 + t;
  int v = (i < NN) ? cnt[i] : 0;
  s[t] = v;
  __syncthreads();
  for (int off = 1; off < 256; off <<= 1) {
    int x = (t >= off) ? s[t - off] : 0;
    __syncthreads();
    s[t] += x;
    __syncthreads();
  }
  if (i < NN) excl[i] = s[t] - v;
  if (t == 255) part[blockIdx.x] = s[255];
}

__global__ __launch_bounds__(256) void scan2_kernel(int* __restrict__ part, int nb) {
  __shared__ int s[256];
  int t = threadIdx.x;
  int v = (t < nb) ? part[t] : 0;
  s[t] = v;
  __syncthreads();
  for (int off = 1; off < 256; off <<= 1) {
    int x = (t >= off) ? s[t - off] : 0;
    __syncthreads();
    s[t] += x;
    __syncthreads();
  }
  if (t < nb) part[t] = s[t] - v;
}

__global__ __launch_bounds__(256) void scan3_kernel(int* __restrict__ excl,
                                                    const int* __restrict__ part,
                                                    int* __restrict__ cursor) {
  int i = blockIdx.x * 256 + threadIdx.x;
  if (i < NN) {
    int e = excl[i] + part[i >> 8];
    excl[i] = e;
    cursor[i] = e;
  }
}

__global__ __launch_bounds__(256) void scatter_kernel(
    const int* __restrict__ senders, const int* __restrict__ recv,
    int* __restrict__ cursor, int* __restrict__ sendp,
    int* __restrict__ eperm) {
  int i = blockIdx.x * 256 + threadIdx.x;
  if (i < NE) {
    int r = recv[i];
    int pos = atomicAdd(&cursor[r], 1);
    sendp[pos] = senders[i];
    eperm[pos] = i;
  }
}

// ---------------- Hs[v] = sum_{e->v} relu(edges_e @ W0 + b0), atomic-free ----------------
// One 64-lane wave per node; each lane owns 2 output columns; edge rows (64 B)
// are wave-uniform broadcast loads.
__global__ __launch_bounds__(256) void hs_fused_kernel(
    const float* __restrict__ edges, const int* __restrict__ eperm,
    const int* __restrict__ start, const int* __restrict__ endc,
    const float* __restrict__ W0, const float* __restrict__ b0,
    float* __restrict__ Hs) {
  const int t = threadIdx.x;
  const int v = blockIdx.x * 4 + (t >> 6);  // NN % 4 == 0
  const int lane = t & 63;
  const int c = lane * 2;
  // preload W0 columns c, c+1 (16x2 floats = 32 VGPRs)
  float w[16][2];
#pragma unroll
  for (int k = 0; k < 16; ++k) {
    float2 ww = *(const float2*)&W0[(size_t)k * H + c];
    w[k][0] = ww.x; w[k][1] = ww.y;
  }
  const float2 bb = *(const float2*)&b0[c];
  float2 a = make_float2(0.f, 0.f);
  const int je = endc[v];
  for (int j = start[v]; j < je; ++j) {
    int ep = eperm[j];  // wave-uniform
    const float* x = &edges[(size_t)ep * 16];
    float4 x0 = *(const float4*)(x + 0);
    float4 x1 = *(const float4*)(x + 4);
    float4 x2 = *(const float4*)(x + 8);
    float4 x3 = *(const float4*)(x + 12);
    float h0 = bb.x, h1 = bb.y;
    h0 += x0.x * w[0][0];  h1 += x0.x * w[0][1];
    h0 += x0.y * w[1][0];  h1 += x0.y * w[1][1];
    h0 += x0.z * w[2][0];  h1 += x0.z * w[2][1];
    h0 += x0.w * w[3][0];  h1 += x0.w * w[3][1];
    h0 += x1.x * w[4][0];  h1 += x1.x * w[4][1];
    h0 += x1.y * w[5][0];  h1 += x1.y * w[5][1];
    h0 += x1.z * w[6][0];  h1 += x1.z * w[6][1];
    h0 += x1.w * w[7][0];  h1 += x1.w * w[7][1];
    h0 += x2.x * w[8][0];  h1 += x2.x * w[8][1];
    h0 += x2.y * w[9][0];  h1 += x2.y * w[9][1];
    h0 += x2.z * w[10][0]; h1 += x2.z * w[10][1];
    h0 += x2.w * w[11][0]; h1 += x2.w * w[11][1];
    h0 += x3.x * w[12][0]; h1 += x3.x * w[12][1];
    h0 += x3.y * w[13][0]; h1 += x3.y * w[13][1];
    h0 += x3.z * w[14][0]; h1 += x3.z * w[14][1];
    h0 += x3.w * w[15][0]; h1 += x3.w * w[15][1];
    a.x += fmaxf(h0, 0.f);
    a.y += fmaxf(h1, 0.f);
  }
  *(float2*)&Hs[(size_t)v * H + c] = a;
}

// ---------------- B[v] = Hs[v] @ Wc + deg[v] * bc ----------------
__global__ __launch_bounds__(128) void blin_kernel(
    const float* __restrict__ Hs, const float* __restrict__ Wc,
    const float* __restrict__ bc, const int* __restrict__ start,
    const int* __restrict__ endc, float* __restrict__ B) {
  __shared__ float xs[32 * 132];
  const int t = threadIdx.x;
  const int r0 = blockIdx.x * 32;
  {
    const int r = t & 31, q = t >> 5;
    int row = r0 + r;
    if (row >= NN) row = NN - 1;
    const float* src = &Hs[(size_t)row * H + q * 32];
#pragma unroll
    for (int j = 0; j < 8; ++j)
      *(float4*)&xs[r * 132 + q * 32 + j * 4] = *(const float4*)&src[j * 4];
  }
  __syncthreads();
  const int c0 = (t & 31) * 4;
  const int rbase = (t >> 5) * 8;
  const float4 bc4 = *(const float4*)&bc[c0];
  float acc[8][4];
#pragma unroll
  for (int r = 0; r < 8; ++r) {
    int row = r0 + rbase + r;
    if (row >= NN) row = NN - 1;
    float deg = (float)(endc[row] - start[row]);
    acc[r][0] = deg * bc4.x; acc[r][1] = deg * bc4.y;
    acc[r][2] = deg * bc4.z; acc[r][3] = deg * bc4.w;
  }
  mm_block(&xs[rbase * 132], 132, H, Wc, c0, acc);
#pragma unroll
  for (int r = 0; r < 8; ++r) {
    int row = r0 + rbase + r;
    if (row < NN)
      *(float4*)&B[(size_t)row * H + c0] =
          make_float4(acc[r][0], acc[r][1], acc[r][2], acc[r][3]);
  }
}

// ---------------- per-pass: agg[v] = B[v] + sum nt16[sendp[j]] ----------------
__global__ __launch_bounds__(256) void agg_kernel(
    const unsigned short* __restrict__ nt16, const float* __restrict__ Bv,
    const int* __restrict__ start, const int* __restrict__ endc,
    const int* __restrict__ sendp, float* __restrict__ agg) {
  const int t = threadIdx.x;
  const int v = blockIdx.x * 4 + (t >> 6);
  const int c = (t & 63) * 2;
  float2 a = *(const float2*)&Bv[(size_t)v * H + c];
  int j = start[v];
  const int e = endc[v];
  for (; j + 1 < e; j += 2) {
    int s0 = sendp[j], s1 = sendp[j + 1];
    unsigned int p0 = *(const unsigned int*)&nt16[(size_t)s0 * H + c];
    unsigned int p1 = *(const unsigned int*)&nt16[(size_t)s1 * H + c];
    a.x += bf2f(p0 & 0xffffu) + bf2f(p1 & 0xffffu);
    a.y += bf2f(p0 >> 16) + bf2f(p1 >> 16);
  }
  if (j < e) {
    int s0 = sendp[j];
    unsigned int p0 = *(const unsigned int*)&nt16[(size_t)s0 * H + c];
    a.x += bf2f(p0 & 0xffffu);
    a.y += bf2f(p0 >> 16);
  }
  *(float2*)&agg[(size_t)v * H + c] = a;
}

// ---------------- node update + fused nt_next = LN_out @ Wt (bf16) ----------------
template <bool WANT_NT>
__global__ __launch_bounds__(128) void node_update_kernel(
    const float* __restrict__ n, const float* __restrict__ agg,
    const float* __restrict__ W0, const float* __restrict__ b0,
    const float* __restrict__ W1, const float* __restrict__ b1,
    const float* __restrict__ Wn, const float* __restrict__ ln_g,
    const float* __restrict__ ln_b, float* __restrict__ nout,
    const float* __restrict__ Wt, unsigned short* __restrict__ nt16) {
  __shared__ float xs[32 * 260];
  __shared__ float hs[32 * 132];
  const int t = threadIdx.x;
  const int r0 = blockIdx.x * 32;
  {
    const int r = t & 31, q = t >> 5;
    int row = r0 + r;
    if (row >= NN) row = NN - 1;
    const float* srcn = &n[(size_t)row * H + q * 32];
    const float* srca = &agg[(size_t)row * H + q * 32];
#pragma unroll
    for (int j = 0; j < 8; ++j)
      *(float4*)&xs[r * 260 + q * 32 + j * 4] = *(const float4*)&srcn[j * 4];
#pragma unroll
    for (int j = 0; j < 8; ++j)
      *(float4*)&xs[r * 260 + 128 + q * 32 + j * 4] = *(const float4*)&srca[j * 4];
  }
  __syncthreads();

  const int c0 = (t & 31) * 4;
  const int rbase = (t >> 5) * 8;
  float acc[8][4];
  {
    float4 bb = *(const float4*)&b0[c0];
#pragma unroll
    for (int r = 0; r < 8; ++r) { acc[r][0] = bb.x; acc[r][1] = bb.y; acc[r][2] = bb.z; acc[r][3] = bb.w; }
  }
  mm_block(&xs[rbase * 260], 260, 256, W0, c0, acc);
#pragma unroll
  for (int r = 0; r < 8; ++r) {
    float4 h;
    h.x = fmaxf(acc[r][0], 0.f); h.y = fmaxf(acc[r][1], 0.f);
    h.z = fmaxf(acc[r][2], 0.f); h.w = fmaxf(acc[r][3], 0.f);
    *(float4*)&hs[(rbase + r) * 132 + c0] = h;
  }
  __syncthreads();
  {
    float4 bb = *(const float4*)&b1[c0];
#pragma unroll
    for (int r = 0; r < 8; ++r) { acc[r][0] = bb.x; acc[r][1] = bb.y; acc[r][2] = bb.z; acc[r][3] = bb.w; }
  }
  mm_block(&hs[rbase * 132], 132, H, W1, c0, acc);   // h1 @ W1 + b1
  mm_block(&xs[rbase * 260], 260, H, Wn, c0, acc);   // + n @ W_node

  const float4 g4 = *(const float4*)&ln_g[c0];
  const float4 bb4 = *(const float4*)&ln_b[c0];
  float o[8][4];
#pragma unroll
  for (int r = 0; r < 8; ++r) {
    float s1 = acc[r][0] + acc[r][1] + acc[r][2] + acc[r][3];
    float s2 = acc[r][0] * acc[r][0] + acc[r][1] * acc[r][1] +
               acc[r][2] * acc[r][2] + acc[r][3] * acc[r][3];
#pragma unroll
    for (int m = 16; m >= 1; m >>= 1) {
      s1 += __shfl_xor(s1, m);
      s2 += __shfl_xor(s2, m);
    }
    float mu = s1 * (1.f / 128.f);
    float var = s2 * (1.f / 128.f) - mu * mu;
    float rs = rsqrtf(var + LN_EPS);
    o[r][0] = (acc[r][0] - mu) * rs * g4.x + bb4.x;
    o[r][1] = (acc[r][1] - mu) * rs * g4.y + bb4.y;
    o[r][2] = (acc[r][2] - mu) * rs * g4.z + bb4.z;
    o[r][3] = (acc[r][3] - mu) * rs * g4.w + bb4.w;
    int row = r0 + rbase + r;
    if (row < NN)
      *(float4*)&nout[(size_t)row * H + c0] =
          make_float4(o[r][0], o[r][1], o[r][2], o[r][3]);
  }

  if constexpr (WANT_NT) {
    __syncthreads();  // all reads of hs (W1 mm) are done
#pragma unroll
    for (int r = 0; r < 8; ++r)
      *(float4*)&hs[(rbase + r) * 132 + c0] =
          make_float4(o[r][0], o[r][1], o[r][2], o[r][3]);
    __syncthreads();
#pragma unroll
    for (int r = 0; r < 8; ++r) { acc[r][0] = 0.f; acc[r][1] = 0.f; acc[r][2] = 0.f; acc[r][3] = 0.f; }
    mm_block(&hs[rbase * 132], 132, H, Wt, c0, acc);
#pragma unroll
    for (int r = 0; r < 8; ++r) {
      int row = r0 + rbase + r;
      if (row < NN) {
        ushort4 pk;
        pk.x = f2bf(acc[r][0]); pk.y = f2bf(acc[r][1]);
        pk.z = f2bf(acc[r][2]); pk.w = f2bf(acc[r][3]);
        *(ushort4*)&nt16[(size_t)row * H + c0] = pk;
      }
    }
  }
}

// ---------------- decoder ----------------
__global__ __launch_bounds__(128) void decode_kernel(
    const float* __restrict__ n, const float* __restrict__ W0,
    const float* __restrict__ b0, const float* __restrict__ W1,
    const float* __restrict__ b1, float* __restrict__ out) {
  __shared__ float xs[32 * 132];
  __shared__ float hs[32 * 132];
  const int t = threadIdx.x;
  const int r0 = blockIdx.x * 32;
  {
    const int r = t & 31, q = t >> 5;
    int row = r0 + r;
    if (row >= NN) row = NN - 1;
    const float* src = &n[(size_t)row * H + q * 32];
#pragma unroll
    for (int j = 0; j < 8; ++j)
      *(float4*)&xs[r * 132 + q * 32 + j * 4] = *(const float4*)&src[j * 4];
  }
  __syncthreads();
  const int c0 = (t & 31) * 4;
  const int rbase = (t >> 5) * 8;
  float acc[8][4];
  {
    float4 bb = *(const float4*)&b0[c0];
#pragma unroll
    for (int r = 0; r < 8; ++r) { acc[r][0] = bb.x; acc[r][1] = bb.y; acc[r][2] = bb.z; acc[r][3] = bb.w; }
  }
  mm_block(&xs[rbase * 132], 132, H, W0, c0, acc);
#pragma unroll
  for (int r = 0; r < 8; ++r) {
    float4 h;
    h.x = fmaxf(acc[r][0], 0.f); h.y = fmaxf(acc[r][1], 0.f);
    h.z = fmaxf(acc[r][2], 0.f); h.w = fmaxf(acc[r][3], 0.f);
    *(float4*)&hs[(rbase + r) * 132 + c0] = h;
  }
  __syncthreads();
  if (t < 64) {
    int r = t >> 1, c = t & 1;
    float s = b1[c];
    for (int k = 0; k < H; ++k) s += hs[r * 132 + k] * W1[k * 2 + c];
    int row = r0 + r;
    if (row < NN) out[(size_t)row * 2 + c] = s;
  }
}

__global__ __launch_bounds__(256) void zero_kernel(float4* __restrict__ p, int n4) {
  int i = blockIdx.x * 256 + threadIdx.x;
  if (i < n4) p[i] = make_float4(0.f, 0.f, 0.f, 0.f);
}

}  // namespace

extern "C" void kernel_launch(void* const* d_in, const int* in_sizes, int n_in,
                              void* d_out, int out_size, void* d_ws, size_t ws_size,
                              hipStream_t stream) {
  const float* nodes     = (const float*)d_in[0];
  const float* edges     = (const float*)d_in[1];
  const int*   senders   = (const int*)d_in[2];
  const int*   receivers = (const int*)d_in[3];
  const float* enc_n_W0 = (const float*)d_in[4];
  const float* enc_n_b0 = (const float*)d_in[5];
  const float* enc_n_W1 = (const float*)d_in[6];
  const float* enc_n_b1 = (const float*)d_in[7];
  const float* enc_e_W0 = (const float*)d_in[8];
  const float* enc_e_b0 = (const float*)d_in[9];
  const float* enc_e_W1 = (const float*)d_in[10];
  const float* enc_e_b1 = (const float*)d_in[11];
  const float* W_msg    = (const float*)d_in[12];
  const float* node_W0  = (const float*)d_in[13];
  const float* node_b0  = (const float*)d_in[14];
  const float* node_W1  = (const float*)d_in[15];
  const float* node_b1  = (const float*)d_in[16];
  const float* W_node   = (const float*)d_in[17];
  const float* ln_g     = (const float*)d_in[18];
  const float* ln_b     = (const float*)d_in[19];
  const float* dec_W0   = (const float*)d_in[20];
  const float* dec_b0   = (const float*)d_in[21];
  const float* dec_W1   = (const float*)d_in[22];
  const float* dec_b1   = (const float*)d_in[23];
  float* out = (float*)d_out;

  const float* Wt = W_msg;                 // rows 0..127 of W_msg
  const float* Wb = W_msg + 128 * H;       // rows 128..255

  // workspace layout (~146 MB)
  float* n0   = (float*)d_ws;
  float* n1   = n0 + (size_t)NN * H;
  float* agg  = n1 + (size_t)NN * H;
  float* B    = agg + (size_t)NN * H;
  float* Hs   = B + (size_t)NN * H;
  float* Wc   = Hs + (size_t)NN * H;       // 128*128
  float* bc   = Wc + 128 * H;              // 128
  unsigned short* nt16 = (unsigned short*)(bc + 128);  // NN*H bf16
  int* cnt    = (int*)(nt16 + (size_t)NN * H);
  int* excl   = cnt + NN;
  int* cursor = excl + NN;
  int* part   = cursor + NN;               // 256
  int* sendp  = part + 256;                // NE
  int* eperm  = sendp + NE;                // NE

  const int nodeBlocks = (NN + 31) / 32;   // 1563
  const int scanBlocks = (NN + 255) / 256; // 196
  const int neBlocks   = (NE + 255) / 256; // 2344

  // --- one-time per launch: sort edges by receiver; fold edge MLP into B ---
  zero_kernel<<<(NN + 63) / 64, 256, 0, stream>>>((float4*)cnt, NN / 4);
  hist_kernel<<<neBlocks, 256, 0, stream>>>(receivers, cnt);
  scan1_kernel<<<scanBlocks, 256, 0, stream>>>(cnt, excl, part);
  scan2_kernel<<<1, 256, 0, stream>>>(part, scanBlocks);
  scan3_kernel<<<scanBlocks, 256, 0, stream>>>(excl, part, cursor);
  scatter_kernel<<<neBlocks, 256, 0, stream>>>(senders, receivers, cursor, sendp, eperm);

  linear_kernel<false><<<4, 128, 0, stream>>>(enc_e_W1, Wb, Wc, 128);  // Wc = W1 @ Wb
  bc_kernel<<<1, 128, 0, stream>>>(enc_e_b1, Wb, bc);                  // bc = b1 @ Wb
  encoder_kernel<32><<<nodeBlocks, 128, 0, stream>>>(
      nodes, enc_n_W0, enc_n_b0, enc_n_W1, enc_n_b1, n0, NN);
  hs_fused_kernel<<<NN / 4, 256, 0, stream>>>(
      edges, eperm, excl, cursor, enc_e_W0, enc_e_b0, Hs);
  blin_kernel<<<nodeBlocks, 128, 0, stream>>>(Hs, Wc, bc, excl, cursor, B);
  linear_kernel<true><<<nodeBlocks, 128, 0, stream>>>(n0, Wt, nt16, NN);  // nt for pass 0

  // --- 5 weight-tied passes ---
  float* ncur = n0;
  float* nnxt = n1;
  for (int p = 0; p < 5; ++p) {
    agg_kernel<<<NN / 4, 256, 0, stream>>>(nt16, B, excl, cursor, sendp, agg);
    if (p < 4)
      node_update_kernel<true><<<nodeBlocks, 128, 0, stream>>>(
          ncur, agg, node_W0, node_b0, node_W1, node_b1, W_node, ln_g, ln_b,
          nnxt, Wt, nt16);
    else
      node_update_kernel<false><<<nodeBlocks, 128, 0, stream>>>(
          ncur, agg, node_W0, node_b0, node_W1, node_b1, W_node, ln_g, ln_b,
          nnxt, Wt, nt16);
    float* tmp = ncur; ncur = nnxt; nnxt = tmp;
  }

  decode_kernel<<<nodeBlocks, 128, 0, stream>>>(ncur, dec_W0, dec_b0, dec_W1, dec_b1, out);
}

// Round 4
// 812.806 us; speedup vs baseline: 8.2208x; 1.9120x over previous
//
#include <hip/hip_runtime.h>

#define DEVFN __device__ __forceinline__

namespace {

constexpr int NN = 50000;   // nodes
constexpr int NE = 600000;  // edges
constexpr int H  = 128;
constexpr float LN_EPS = 1e-6f;

typedef _Float16 f16x8 __attribute__((ext_vector_type(8)));
typedef _Float16 f16x4 __attribute__((ext_vector_type(4)));
typedef _Float16 f16x2 __attribute__((ext_vector_type(2)));
typedef float f32x4 __attribute__((ext_vector_type(4)));

// acc[8][4] += xs_tile(8 rows x K) @ W(K x 128) restricted to cols c0..c0+3.
DEVFN void mm_block(const float* xsrow, int pitch, int K,
                    const float* __restrict__ W, int c0, float (&acc)[8][4]) {
  for (int k = 0; k < K; k += 4) {
    float4 w0 = *(const float4*)(W + (size_t)(k + 0) * H + c0);
    float4 w1 = *(const float4*)(W + (size_t)(k + 1) * H + c0);
    float4 w2 = *(const float4*)(W + (size_t)(k + 2) * H + c0);
    float4 w3 = *(const float4*)(W + (size_t)(k + 3) * H + c0);
#pragma unroll
    for (int r = 0; r < 8; ++r) {
      float4 a = *(const float4*)(xsrow + r * pitch + k);
      acc[r][0] += a.x * w0.x; acc[r][0] += a.y * w1.x; acc[r][0] += a.z * w2.x; acc[r][0] += a.w * w3.x;
      acc[r][1] += a.x * w0.y; acc[r][1] += a.y * w1.y; acc[r][1] += a.z * w2.y; acc[r][1] += a.w * w3.y;
      acc[r][2] += a.x * w0.z; acc[r][2] += a.y * w1.z; acc[r][2] += a.z * w2.z; acc[r][2] += a.w * w3.z;
      acc[r][3] += a.x * w0.w; acc[r][3] += a.y * w1.w; acc[r][3] += a.z * w2.w; acc[r][3] += a.w * w3.w;
    }
  }
}

// ---------------- node encoder (2-layer MLP, ReLU between), fp16 out ----------------
template <int K_IN>
__global__ __launch_bounds__(128) void encoder_kernel(
    const float* __restrict__ x, const float* __restrict__ W0,
    const float* __restrict__ b0, const float* __restrict__ W1,
    const float* __restrict__ b1, _Float16* __restrict__ outp, int R) {
  constexpr int PIN = K_IN + 4;
  __shared__ float xs[32 * PIN];
  __shared__ float hs[32 * 132];
  const int t = threadIdx.x;
  const int r0 = blockIdx.x * 32;

  const int nvec = 32 * K_IN / 4;
  for (int i = t; i < nvec; i += 128) {
    int rr = i / (K_IN / 4);
    int kk = (i % (K_IN / 4)) * 4;
    int row = r0 + rr;
    float4 v = make_float4(0.f, 0.f, 0.f, 0.f);
    if (row < R) v = *(const float4*)&x[(size_t)row * K_IN + kk];
    *(float4*)&xs[rr * PIN + kk] = v;
  }
  __syncthreads();

  const int c0 = (t & 31) * 4;
  const int rbase = (t >> 5) * 8;
  float acc[8][4];
  {
    float4 bb = *(const float4*)&b0[c0];
#pragma unroll
    for (int r = 0; r < 8; ++r) { acc[r][0] = bb.x; acc[r][1] = bb.y; acc[r][2] = bb.z; acc[r][3] = bb.w; }
  }
  mm_block(&xs[rbase * PIN], PIN, K_IN, W0, c0, acc);
#pragma unroll
  for (int r = 0; r < 8; ++r) {
    float4 h;
    h.x = fmaxf(acc[r][0], 0.f); h.y = fmaxf(acc[r][1], 0.f);
    h.z = fmaxf(acc[r][2], 0.f); h.w = fmaxf(acc[r][3], 0.f);
    *(float4*)&hs[(rbase + r) * 132 + c0] = h;
  }
  __syncthreads();
  {
    float4 bb = *(const float4*)&b1[c0];
#pragma unroll
    for (int r = 0; r < 8; ++r) { acc[r][0] = bb.x; acc[r][1] = bb.y; acc[r][2] = bb.z; acc[r][3] = bb.w; }
  }
  mm_block(&hs[rbase * 132], 132, H, W1, c0, acc);
#pragma unroll
  for (int r = 0; r < 8; ++r) {
    int row = r0 + rbase + r;
    if (row < R) {
      f16x4 pk = {(_Float16)acc[r][0], (_Float16)acc[r][1],
                  (_Float16)acc[r][2], (_Float16)acc[r][3]};
      *(f16x4*)&outp[(size_t)row * H + c0] = pk;
    }
  }
}

// ---------------- fp32 linear (used once for Wc = W1 @ Wb) ----------------
__global__ __launch_bounds__(128) void linear_kernel(
    const float* __restrict__ x, const float* __restrict__ W,
    float* __restrict__ y, int R) {
  __shared__ float xs[32 * 132];
  const int t = threadIdx.x;
  const int r0 = blockIdx.x * 32;
  {
    const int r = t & 31, q = t >> 5;
    int row = r0 + r;
    if (row >= R) row = R - 1;
    const float* src = &x[(size_t)row * H + q * 32];
#pragma unroll
    for (int j = 0; j < 8; ++j)
      *(float4*)&xs[r * 132 + q * 32 + j * 4] = *(const float4*)&src[j * 4];
  }
  __syncthreads();
  const int c0 = (t & 31) * 4;
  const int rbase = (t >> 5) * 8;
  float acc[8][4];
#pragma unroll
  for (int r = 0; r < 8; ++r) { acc[r][0] = 0.f; acc[r][1] = 0.f; acc[r][2] = 0.f; acc[r][3] = 0.f; }
  mm_block(&xs[rbase * 132], 132, H, W, c0, acc);
#pragma unroll
  for (int r = 0; r < 8; ++r) {
    int row = r0 + rbase + r;
    if (row < R)
      *(float4*)&y[(size_t)row * H + c0] =
          make_float4(acc[r][0], acc[r][1], acc[r][2], acc[r][3]);
  }
}

// bc[j] = sum_k b1[k] * Wb[k*128 + j]
__global__ __launch_bounds__(128) void bc_kernel(
    const float* __restrict__ b1, const float* __restrict__ Wb,
    float* __restrict__ bc) {
  int j = threadIdx.x;
  float s = 0.f;
  for (int k = 0; k < H; ++k) s += b1[k] * Wb[(size_t)k * H + j];
  bc[j] = s;
}

// ---------------- prepack W[K x 128] fp32 -> MFMA B-fragment order, fp16 ----------------
// pk[((ks*8 + ct)*64 + lane)*8 + j] = W[ks*32 + (lane>>4)*8 + j][ct*16 + (lane&15)]
__global__ __launch_bounds__(64) void prepack_kernel(
    const float* __restrict__ W, _Float16* __restrict__ pk) {
  const int ks = blockIdx.x, ct = blockIdx.y, l = threadIdx.x;
  const int kbase = ks * 32 + (l >> 4) * 8;
  const int col = ct * 16 + (l & 15);
  _Float16 tmp[8];
#pragma unroll
  for (int j = 0; j < 8; ++j)
    tmp[j] = (_Float16)W[(size_t)(kbase + j) * H + col];
  *(f16x8*)&pk[((size_t)((ks * 8 + ct) * 64) + l) * 8] = *(f16x8*)tmp;
}

// ---------------- counting sort by receiver ----------------
__global__ __launch_bounds__(256) void hist_kernel(const int* __restrict__ recv,
                                                   int* __restrict__ cnt) {
  int i = blockIdx.x * 256 + threadIdx.x;
  if (i < NE) atomicAdd(&cnt[recv[i]], 1);
}

__global__ __launch_bounds__(256) void scan1_kernel(const int* __restrict__ cnt,
                                                    int* __restrict__ excl,
                                                    int* __restrict__ part) {
  __shared__ int s[256];
  int t = threadIdx.x;
  int i = blockIdx.x * 256 + t;
  int v = (i < NN) ? cnt[i] : 0;
  s[t] = v;
  __syncthreads();
  for (int off = 1; off < 256; off <<= 1) {
    int x = (t >= off) ? s[t - off] : 0;
    __syncthreads();
    s[t] += x;
    __syncthreads();
  }
  if (i < NN) excl[i] = s[t] - v;
  if (t == 255) part[blockIdx.x] = s[255];
}

__global__ __launch_bounds__(256) void scan2_kernel(int* __restrict__ part, int nb) {
  __shared__ int s[256];
  int t = threadIdx.x;
  int v = (t < nb) ? part[t] : 0;
  s[t] = v;
  __syncthreads();
  for (int off = 1; off < 256; off <<= 1) {
    int x = (t >= off) ? s[t - off] : 0;
    __syncthreads();
    s[t] += x;
    __syncthreads();
  }
  if (t < nb) part[t] = s[t] - v;
}

__global__ __launch_bounds__(256) void scan3_kernel(int* __restrict__ excl,
                                                    const int* __restrict__ part,
                                                    int* __restrict__ cursor) {
  int i = blockIdx.x * 256 + threadIdx.x;
  if (i < NN) {
    int e = excl[i] + part[i >> 8];
    excl[i] = e;
    cursor[i] = e;
  }
}

__global__ __launch_bounds__(256) void scatter_kernel(
    const int* __restrict__ senders, const int* __restrict__ recv,
    int* __restrict__ cursor, int* __restrict__ sendp,
    int* __restrict__ eperm) {
  int i = blockIdx.x * 256 + threadIdx.x;
  if (i < NE) {
    int r = recv[i];
    int pos = atomicAdd(&cursor[r], 1);
    sendp[pos] = senders[i];
    eperm[pos] = i;
  }
}

// ---------------- Hs[v] = sum_{e->v} relu(edges_e @ W0 + b0), atomic-free ----------------
__global__ __launch_bounds__(256) void hs_fused_kernel(
    const float* __restrict__ edges, const int* __restrict__ eperm,
    const int* __restrict__ start, const int* __restrict__ endc,
    const float* __restrict__ W0, const float* __restrict__ b0,
    float* __restrict__ Hs) {
  const int t = threadIdx.x;
  const int v = blockIdx.x * 4 + (t >> 6);
  const int lane = t & 63;
  const int c = lane * 2;
  float w[16][2];
#pragma unroll
  for (int k = 0; k < 16; ++k) {
    float2 ww = *(const float2*)&W0[(size_t)k * H + c];
    w[k][0] = ww.x; w[k][1] = ww.y;
  }
  const float2 bb = *(const float2*)&b0[c];
  float2 a = make_float2(0.f, 0.f);
  const int je = endc[v];
  for (int j = start[v]; j < je; ++j) {
    int ep = eperm[j];
    const float* x = &edges[(size_t)ep * 16];
    float4 x0 = *(const float4*)(x + 0);
    float4 x1 = *(const float4*)(x + 4);
    float4 x2 = *(const float4*)(x + 8);
    float4 x3 = *(const float4*)(x + 12);
    float h0 = bb.x, h1 = bb.y;
    h0 += x0.x * w[0][0];  h1 += x0.x * w[0][1];
    h0 += x0.y * w[1][0];  h1 += x0.y * w[1][1];
    h0 += x0.z * w[2][0];  h1 += x0.z * w[2][1];
    h0 += x0.w * w[3][0];  h1 += x0.w * w[3][1];
    h0 += x1.x * w[4][0];  h1 += x1.x * w[4][1];
    h0 += x1.y * w[5][0];  h1 += x1.y * w[5][1];
    h0 += x1.z * w[6][0];  h1 += x1.z * w[6][1];
    h0 += x1.w * w[7][0];  h1 += x1.w * w[7][1];
    h0 += x2.x * w[8][0];  h1 += x2.x * w[8][1];
    h0 += x2.y * w[9][0];  h1 += x2.y * w[9][1];
    h0 += x2.z * w[10][0]; h1 += x2.z * w[10][1];
    h0 += x2.w * w[11][0]; h1 += x2.w * w[11][1];
    h0 += x3.x * w[12][0]; h1 += x3.x * w[12][1];
    h0 += x3.y * w[13][0]; h1 += x3.y * w[13][1];
    h0 += x3.z * w[14][0]; h1 += x3.z * w[14][1];
    h0 += x3.w * w[15][0]; h1 += x3.w * w[15][1];
    a.x += fmaxf(h0, 0.f);
    a.y += fmaxf(h1, 0.f);
  }
  *(float2*)&Hs[(size_t)v * H + c] = a;
}

// ---------------- B[v] = Hs[v] @ Wc + deg[v] * bc ----------------
__global__ __launch_bounds__(128) void blin_kernel(
    const float* __restrict__ Hs, const float* __restrict__ Wc,
    const float* __restrict__ bc, const int* __restrict__ start,
    const int* __restrict__ endc, float* __restrict__ B) {
  __shared__ float xs[32 * 132];
  const int t = threadIdx.x;
  const int r0 = blockIdx.x * 32;
  {
    const int r = t & 31, q = t >> 5;
    int row = r0 + r;
    if (row >= NN) row = NN - 1;
    const float* src = &Hs[(size_t)row * H + q * 32];
#pragma unroll
    for (int j = 0; j < 8; ++j)
      *(float4*)&xs[r * 132 + q * 32 + j * 4] = *(const float4*)&src[j * 4];
  }
  __syncthreads();
  const int c0 = (t & 31) * 4;
  const int rbase = (t >> 5) * 8;
  const float4 bc4 = *(const float4*)&bc[c0];
  float acc[8][4];
#pragma unroll
  for (int r = 0; r < 8; ++r) {
    int row = r0 + rbase + r;
    if (row >= NN) row = NN - 1;
    float deg = (float)(endc[row] - start[row]);
    acc[r][0] = deg * bc4.x; acc[r][1] = deg * bc4.y;
    acc[r][2] = deg * bc4.z; acc[r][3] = deg * bc4.w;
  }
  mm_block(&xs[rbase * 132], 132, H, Wc, c0, acc);
#pragma unroll
  for (int r = 0; r < 8; ++r) {
    int row = r0 + rbase + r;
    if (row < NN)
      *(float4*)&B[(size_t)row * H + c0] =
          make_float4(acc[r][0], acc[r][1], acc[r][2], acc[r][3]);
  }
}

// ---------------- per-pass: agg[v] = B[v] + sum nt[sendp[j]]  (fp16 in/out) ----------------
__global__ __launch_bounds__(256) void agg_kernel(
    const _Float16* __restrict__ nt, const float* __restrict__ Bv,
    const int* __restrict__ start, const int* __restrict__ endc,
    const int* __restrict__ sendp, _Float16* __restrict__ agg) {
  const int t = threadIdx.x;
  const int v = blockIdx.x * 4 + (t >> 6);
  const int c = (t & 63) * 2;
  float2 a = *(const float2*)&Bv[(size_t)v * H + c];
  int j = start[v];
  const int e = endc[v];
  for (; j + 1 < e; j += 2) {
    int s0 = sendp[j], s1 = sendp[j + 1];
    f16x2 p0 = *(const f16x2*)&nt[(size_t)s0 * H + c];
    f16x2 p1 = *(const f16x2*)&nt[(size_t)s1 * H + c];
    a.x += (float)p0[0] + (float)p1[0];
    a.y += (float)p0[1] + (float)p1[1];
  }
  if (j < e) {
    int s0 = sendp[j];
    f16x2 p0 = *(const f16x2*)&nt[(size_t)s0 * H + c];
    a.x += (float)p0[0];
    a.y += (float)p0[1];
  }
  f16x2 o = {(_Float16)a.x, (_Float16)a.y};
  *(f16x2*)&agg[(size_t)v * H + c] = o;
}

// ---------------- MFMA node update ----------------
// 256 thr = 4 waves, 64 rows/block (16/wave). 16x16x32 f16 MFMA.
// A[m=lane&15][k=quad*8+j]; B prepacked [k=quad*8+j][n=lane&15]; C/D col=lane&15,row=quad*4+reg.
template <bool WANT_NT>
__global__ __launch_bounds__(256) void node_mfma_kernel(
    const _Float16* __restrict__ n16, const _Float16* __restrict__ agg16,
    const _Float16* __restrict__ pkW0, const float* __restrict__ b0,
    const _Float16* __restrict__ pkW1, const float* __restrict__ b1,
    const _Float16* __restrict__ pkWn, const _Float16* __restrict__ pkWt,
    const float* __restrict__ ln_g, const float* __restrict__ ln_b,
    _Float16* __restrict__ nout, _Float16* __restrict__ ntout) {
  __shared__ _Float16 lds[4][16 * 136];
  const int t = threadIdx.x;
  const int wave = t >> 6, lane = t & 63;
  const int row0 = blockIdx.x * 64 + wave * 16;
  const int quad = lane >> 4, m16 = lane & 15;
  _Float16* hlds = &lds[wave][0];

  int arow = row0 + m16;
  if (arow >= NN) arow = NN - 1;
  const _Float16* nrow = &n16[(size_t)arow * H + quad * 8];
  const _Float16* grow = &agg16[(size_t)arow * H + quad * 8];

  // ---- h = relu(concat(n,agg) @ W0 + b0) ----
  f32x4 acc[8];
#pragma unroll
  for (int ct = 0; ct < 8; ++ct) {
    float bb = b0[ct * 16 + m16];
    acc[ct] = (f32x4){bb, bb, bb, bb};
  }
#pragma unroll
  for (int ks = 0; ks < 8; ++ks) {
    f16x8 a = (ks < 4) ? *(const f16x8*)(nrow + ks * 32)
                       : *(const f16x8*)(grow + (ks - 4) * 32);
    const _Float16* bp = pkW0 + ((size_t)ks * 8 * 64 + lane) * 8;
#pragma unroll
    for (int ct = 0; ct < 8; ++ct) {
      f16x8 b = *(const f16x8*)(bp + ct * 512);
      acc[ct] = __builtin_amdgcn_mfma_f32_16x16x32_f16(a, b, acc[ct], 0, 0, 0);
    }
  }
  // transpose h into wave-local LDS (row-major, pitch 136)
#pragma unroll
  for (int ct = 0; ct < 8; ++ct) {
#pragma unroll
    for (int q = 0; q < 4; ++q)
      hlds[(quad * 4 + q) * 136 + ct * 16 + m16] =
          (_Float16)fmaxf(acc[ct][q], 0.f);
  }
  __syncthreads();

  // ---- acc2 = h @ W1 + b1 + n @ Wn ----
  const _Float16* hrow = &hlds[m16 * 136 + quad * 8];
  f32x4 acc2[8];
#pragma unroll
  for (int ct = 0; ct < 8; ++ct) {
    float bb = b1[ct * 16 + m16];
    acc2[ct] = (f32x4){bb, bb, bb, bb};
  }
#pragma unroll
  for (int ks = 0; ks < 4; ++ks) {
    f16x8 ah = *(const f16x8*)(hrow + ks * 32);
    f16x8 an = *(const f16x8*)(nrow + ks * 32);
    const _Float16* bp1 = pkW1 + ((size_t)ks * 8 * 64 + lane) * 8;
    const _Float16* bpn = pkWn + ((size_t)ks * 8 * 64 + lane) * 8;
#pragma unroll
    for (int ct = 0; ct < 8; ++ct) {
      f16x8 b1f = *(const f16x8*)(bp1 + ct * 512);
      acc2[ct] = __builtin_amdgcn_mfma_f32_16x16x32_f16(ah, b1f, acc2[ct], 0, 0, 0);
      f16x8 bnf = *(const f16x8*)(bpn + ct * 512);
      acc2[ct] = __builtin_amdgcn_mfma_f32_16x16x32_f16(an, bnf, acc2[ct], 0, 0, 0);
    }
  }

  // ---- LayerNorm across the 128 cols of each row ----
  float gv[8], bv[8];
#pragma unroll
  for (int ct = 0; ct < 8; ++ct) {
    gv[ct] = ln_g[ct * 16 + m16];
    bv[ct] = ln_b[ct * 16 + m16];
  }
  __syncthreads();  // all reads of hlds (W1 A-frags) complete before overwrite
#pragma unroll
  for (int q = 0; q < 4; ++q) {
    float s1 = 0.f, s2 = 0.f;
#pragma unroll
    for (int ct = 0; ct < 8; ++ct) {
      float v = acc2[ct][q];
      s1 += v; s2 += v * v;
    }
#pragma unroll
    for (int m = 1; m <= 8; m <<= 1) {
      s1 += __shfl_xor(s1, m);
      s2 += __shfl_xor(s2, m);
    }
    float mu = s1 * (1.f / 128.f);
    float var = s2 * (1.f / 128.f) - mu * mu;
    float rs = rsqrtf(var + LN_EPS);
#pragma unroll
    for (int ct = 0; ct < 8; ++ct) {
      float o = (acc2[ct][q] - mu) * rs * gv[ct] + bv[ct];
      hlds[(quad * 4 + q) * 136 + ct * 16 + m16] = (_Float16)o;
    }
  }
  __syncthreads();

  // linear store of LN output (fp16 row-major)
  {
    int lr = lane >> 2;
    int cc = (lane & 3) * 32;
    const _Float16* src = &hlds[lr * 136 + cc];
    int grow2 = row0 + lr;
    if (grow2 < NN) {
      _Float16* dst = &nout[(size_t)grow2 * H + cc];
      *(f16x8*)(dst + 0)  = *(const f16x8*)(src + 0);
      *(f16x8*)(dst + 8)  = *(const f16x8*)(src + 8);
      *(f16x8*)(dst + 16) = *(const f16x8*)(src + 16);
      *(f16x8*)(dst + 24) = *(const f16x8*)(src + 24);
    }
  }

  if constexpr (WANT_NT) {
    // nt = LN_out @ Wt (A-frags re-read from hlds)
    f32x4 acc3[8];
#pragma unroll
    for (int ct = 0; ct < 8; ++ct) acc3[ct] = (f32x4){0.f, 0.f, 0.f, 0.f};
#pragma unroll
    for (int ks = 0; ks < 4; ++ks) {
      f16x8 a = *(const f16x8*)(hrow + ks * 32);
      const _Float16* bp = pkWt + ((size_t)ks * 8 * 64 + lane) * 8;
#pragma unroll
      for (int ct = 0; ct < 8; ++ct) {
        f16x8 b = *(const f16x8*)(bp + ct * 512);
        acc3[ct] = __builtin_amdgcn_mfma_f32_16x16x32_f16(a, b, acc3[ct], 0, 0, 0);
      }
    }
    __syncthreads();  // reads of hlds done everywhere before overwrite
#pragma unroll
    for (int ct = 0; ct < 8; ++ct) {
#pragma unroll
      for (int q = 0; q < 4; ++q)
        hlds[(quad * 4 + q) * 136 + ct * 16 + m16] = (_Float16)acc3[ct][q];
    }
    __syncthreads();
    {
      int lr = lane >> 2;
      int cc = (lane & 3) * 32;
      const _Float16* src = &hlds[lr * 136 + cc];
      int grow2 = row0 + lr;
      if (grow2 < NN) {
        _Float16* dst = &ntout[(size_t)grow2 * H + cc];
        *(f16x8*)(dst + 0)  = *(const f16x8*)(src + 0);
        *(f16x8*)(dst + 8)  = *(const f16x8*)(src + 8);
        *(f16x8*)(dst + 16) = *(const f16x8*)(src + 16);
        *(f16x8*)(dst + 24) = *(const f16x8*)(src + 24);
      }
    }
  }
}

// ---------------- MFMA linear: Y = X @ W (fp16 in/out, K=128) ----------------
__global__ __launch_bounds__(256) void mfma_linear_kernel(
    const _Float16* __restrict__ X, const _Float16* __restrict__ pkW,
    _Float16* __restrict__ Y) {
  __shared__ _Float16 lds[4][16 * 136];
  const int t = threadIdx.x;
  const int wave = t >> 6, lane = t & 63;
  const int row0 = blockIdx.x * 64 + wave * 16;
  const int quad = lane >> 4, m16 = lane & 15;
  _Float16* hlds = &lds[wave][0];
  int arow = row0 + m16;
  if (arow >= NN) arow = NN - 1;
  const _Float16* xr = &X[(size_t)arow * H + quad * 8];
  f32x4 acc[8];
#pragma unroll
  for (int ct = 0; ct < 8; ++ct) acc[ct] = (f32x4){0.f, 0.f, 0.f, 0.f};
#pragma unroll
  for (int ks = 0; ks < 4; ++ks) {
    f16x8 a = *(const f16x8*)(xr + ks * 32);
    const _Float16* bp = pkW + ((size_t)ks * 8 * 64 + lane) * 8;
#pragma unroll
    for (int ct = 0; ct < 8; ++ct) {
      f16x8 b = *(const f16x8*)(bp + ct * 512);
      acc[ct] = __builtin_amdgcn_mfma_f32_16x16x32_f16(a, b, acc[ct], 0, 0, 0);
    }
  }
#pragma unroll
  for (int ct = 0; ct < 8; ++ct) {
#pragma unroll
    for (int q = 0; q < 4; ++q)
      hlds[(quad * 4 + q) * 136 + ct * 16 + m16] = (_Float16)acc[ct][q];
  }
  __syncthreads();
  {
    int lr = lane >> 2;
    int cc = (lane & 3) * 32;
    const _Float16* src = &hlds[lr * 136 + cc];
    int grow2 = row0 + lr;
    if (grow2 < NN) {
      _Float16* dst = &Y[(size_t)grow2 * H + cc];
      *(f16x8*)(dst + 0)  = *(const f16x8*)(src + 0);
      *(f16x8*)(dst + 8)  = *(const f16x8*)(src + 8);
      *(f16x8*)(dst + 16) = *(const f16x8*)(src + 16);
      *(f16x8*)(dst + 24) = *(const f16x8*)(src + 24);
    }
  }
}

// ---------------- decoder (fp16 node input) ----------------
__global__ __launch_bounds__(128) void decode_kernel(
    const _Float16* __restrict__ n, const float* __restrict__ W0,
    const float* __restrict__ b0, const float* __restrict__ W1,
    const float* __restrict__ b1, float* __restrict__ out) {
  __shared__ float xs[32 * 132];
  __shared__ float hs[32 * 132];
  const int t = threadIdx.x;
  const int r0 = blockIdx.x * 32;
  {
    const int r = t & 31, q = t >> 5;
    int row = r0 + r;
    if (row >= NN) row = NN - 1;
    const _Float16* src = &n[(size_t)row * H + q * 32];
#pragma unroll
    for (int j = 0; j < 4; ++j) {
      f16x8 v8 = *(const f16x8*)&src[j * 8];
#pragma unroll
      for (int i = 0; i < 8; ++i)
        xs[r * 132 + q * 32 + j * 8 + i] = (float)v8[i];
    }
  }
  __syncthreads();
  const int c0 = (t & 31) * 4;
  const int rbase = (t >> 5) * 8;
  float acc[8][4];
  {
    float4 bb = *(const float4*)&b0[c0];
#pragma unroll
    for (int r = 0; r < 8; ++r) { acc[r][0] = bb.x; acc[r][1] = bb.y; acc[r][2] = bb.z; acc[r][3] = bb.w; }
  }
  mm_block(&xs[rbase * 132], 132, H, W0, c0, acc);
#pragma unroll
  for (int r = 0; r < 8; ++r) {
    float4 h;
    h.x = fmaxf(acc[r][0], 0.f); h.y = fmaxf(acc[r][1], 0.f);
    h.z = fmaxf(acc[r][2], 0.f); h.w = fmaxf(acc[r][3], 0.f);
    *(float4*)&hs[(rbase + r) * 132 + c0] = h;
  }
  __syncthreads();
  if (t < 64) {
    int r = t >> 1, c = t & 1;
    float s = b1[c];
    for (int k = 0; k < H; ++k) s += hs[r * 132 + k] * W1[k * 2 + c];
    int row = r0 + r;
    if (row < NN) out[(size_t)row * 2 + c] = s;
  }
}

__global__ __launch_bounds__(256) void zero_kernel(float4* __restrict__ p, int n4) {
  int i = blockIdx.x * 256 + threadIdx.x;
  if (i < n4) p[i] = make_float4(0.f, 0.f, 0.f, 0.f);
}

}  // namespace

extern "C" void kernel_launch(void* const* d_in, const int* in_sizes, int n_in,
                              void* d_out, int out_size, void* d_ws, size_t ws_size,
                              hipStream_t stream) {
  const float* nodes     = (const float*)d_in[0];
  const float* edges     = (const float*)d_in[1];
  const int*   senders   = (const int*)d_in[2];
  const int*   receivers = (const int*)d_in[3];
  const float* enc_n_W0 = (const float*)d_in[4];
  const float* enc_n_b0 = (const float*)d_in[5];
  const float* enc_n_W1 = (const float*)d_in[6];
  const float* enc_n_b1 = (const float*)d_in[7];
  const float* enc_e_W0 = (const float*)d_in[8];
  const float* enc_e_b0 = (const float*)d_in[9];
  const float* enc_e_W1 = (const float*)d_in[10];
  const float* enc_e_b1 = (const float*)d_in[11];
  const float* W_msg    = (const float*)d_in[12];
  const float* node_W0  = (const float*)d_in[13];
  const float* node_b0  = (const float*)d_in[14];
  const float* node_W1  = (const float*)d_in[15];
  const float* node_b1  = (const float*)d_in[16];
  const float* W_node   = (const float*)d_in[17];
  const float* ln_g     = (const float*)d_in[18];
  const float* ln_b     = (const float*)d_in[19];
  const float* dec_W0   = (const float*)d_in[20];
  const float* dec_b0   = (const float*)d_in[21];
  const float* dec_W1   = (const float*)d_in[22];
  const float* dec_b1   = (const float*)d_in[23];
  float* out = (float*)d_out;

  const float* Wt = W_msg;                 // rows 0..127 of W_msg
  const float* Wb = W_msg + 128 * H;       // rows 128..255

  // workspace layout
  float* B    = (float*)d_ws;                          // NN*H f32
  float* Hs   = B + (size_t)NN * H;                    // NN*H f32
  float* Wc   = Hs + (size_t)NN * H;                   // 128*128 f32
  float* bc   = Wc + 128 * H;                          // 128
  _Float16* n16a  = (_Float16*)(bc + 128);             // NN*H f16
  _Float16* n16b  = n16a + (size_t)NN * H;
  _Float16* agg16 = n16b + (size_t)NN * H;
  _Float16* nt16  = agg16 + (size_t)NN * H;
  _Float16* pkW0  = nt16 + (size_t)NN * H;             // 256*128 f16
  _Float16* pkW1  = pkW0 + 256 * H;                    // 128*128 f16
  _Float16* pkWn  = pkW1 + 128 * H;
  _Float16* pkWt  = pkWn + 128 * H;
  int* cnt    = (int*)(pkWt + 128 * H);
  int* excl   = cnt + NN;
  int* cursor = excl + NN;
  int* part   = cursor + NN;               // 256
  int* sendp  = part + 256;                // NE
  int* eperm  = sendp + NE;                // NE

  const int nodeBlocks = (NN + 31) / 32;     // 1563
  const int mfmaBlocks = (NN + 63) / 64;     // 782
  const int scanBlocks = (NN + 255) / 256;   // 196
  const int neBlocks   = (NE + 255) / 256;   // 2344

  // --- one-time: sort edges by receiver; fold edge MLP into B; prepack weights ---
  zero_kernel<<<(NN / 4 + 255) / 256, 256, 0, stream>>>((float4*)cnt, NN / 4);
  hist_kernel<<<neBlocks, 256, 0, stream>>>(receivers, cnt);
  scan1_kernel<<<scanBlocks, 256, 0, stream>>>(cnt, excl, part);
  scan2_kernel<<<1, 256, 0, stream>>>(part, scanBlocks);
  scan3_kernel<<<scanBlocks, 256, 0, stream>>>(excl, part, cursor);
  scatter_kernel<<<neBlocks, 256, 0, stream>>>(senders, receivers, cursor, sendp, eperm);

  linear_kernel<<<4, 128, 0, stream>>>(enc_e_W1, Wb, Wc, 128);  // Wc = W1 @ Wb
  bc_kernel<<<1, 128, 0, stream>>>(enc_e_b1, Wb, bc);           // bc = b1 @ Wb
  prepack_kernel<<<dim3(8, 8), 64, 0, stream>>>(node_W0, pkW0);
  prepack_kernel<<<dim3(4, 8), 64, 0, stream>>>(node_W1, pkW1);
  prepack_kernel<<<dim3(4, 8), 64, 0, stream>>>(W_node, pkWn);
  prepack_kernel<<<dim3(4, 8), 64, 0, stream>>>(Wt, pkWt);

  encoder_kernel<32><<<nodeBlocks, 128, 0, stream>>>(
      nodes, enc_n_W0, enc_n_b0, enc_n_W1, enc_n_b1, n16a, NN);
  hs_fused_kernel<<<NN / 4, 256, 0, stream>>>(
      edges, eperm, excl, cursor, enc_e_W0, enc_e_b0, Hs);
  blin_kernel<<<nodeBlocks, 128, 0, stream>>>(Hs, Wc, bc, excl, cursor, B);
  mfma_linear_kernel<<<mfmaBlocks, 256, 0, stream>>>(n16a, pkWt, nt16);  // nt for pass 0

  // --- 5 weight-tied passes ---
  _Float16* ncur = n16a;
  _Float16* nnxt = n16b;
  for (int p = 0; p < 5; ++p) {
    agg_kernel<<<NN / 4, 256, 0, stream>>>(nt16, B, excl, cursor, sendp, agg16);
    if (p < 4)
      node_mfma_kernel<true><<<mfmaBlocks, 256, 0, stream>>>(
          ncur, agg16, pkW0, node_b0, pkW1, node_b1, pkWn, pkWt,
          ln_g, ln_b, nnxt, nt16);
    else
      node_mfma_kernel<false><<<mfmaBlocks, 256, 0, stream>>>(
          ncur, agg16, pkW0, node_b0, pkW1, node_b1, pkWn, pkWt,
          ln_g, ln_b, nnxt, nt16);
    _Float16* tmp = ncur; ncur = nnxt; nnxt = tmp;
  }

  decode_kernel<<<nodeBlocks, 128, 0, stream>>>(ncur, dec_W0, dec_b0, dec_W1, dec_b1, out);
}

// Round 5
// 793.516 us; speedup vs baseline: 8.4207x; 1.0243x over previous
//
#include <hip/hip_runtime.h>

#define DEVFN __device__ __forceinline__

namespace {

constexpr int NN = 50000;   // nodes
constexpr int NE = 600000;  // edges
constexpr int H  = 128;
constexpr float LN_EPS = 1e-6f;

typedef _Float16 f16x8 __attribute__((ext_vector_type(8)));
typedef _Float16 f16x4 __attribute__((ext_vector_type(4)));
typedef float f32x4 __attribute__((ext_vector_type(4)));

// acc[8][4] += xs_tile(8 rows x K) @ W(K x 128) restricted to cols c0..c0+3.
DEVFN void mm_block(const float* xsrow, int pitch, int K,
                    const float* __restrict__ W, int c0, float (&acc)[8][4]) {
  for (int k = 0; k < K; k += 4) {
    float4 w0 = *(const float4*)(W + (size_t)(k + 0) * H + c0);
    float4 w1 = *(const float4*)(W + (size_t)(k + 1) * H + c0);
    float4 w2 = *(const float4*)(W + (size_t)(k + 2) * H + c0);
    float4 w3 = *(const float4*)(W + (size_t)(k + 3) * H + c0);
#pragma unroll
    for (int r = 0; r < 8; ++r) {
      float4 a = *(const float4*)(xsrow + r * pitch + k);
      acc[r][0] += a.x * w0.x; acc[r][0] += a.y * w1.x; acc[r][0] += a.z * w2.x; acc[r][0] += a.w * w3.x;
      acc[r][1] += a.x * w0.y; acc[r][1] += a.y * w1.y; acc[r][1] += a.z * w2.y; acc[r][1] += a.w * w3.y;
      acc[r][2] += a.x * w0.z; acc[r][2] += a.y * w1.z; acc[r][2] += a.z * w2.z; acc[r][2] += a.w * w3.z;
      acc[r][3] += a.x * w0.w; acc[r][3] += a.y * w1.w; acc[r][3] += a.z * w2.w; acc[r][3] += a.w * w3.w;
    }
  }
}

// ---------------- node encoder (2-layer MLP, ReLU between), fp16 out ----------------
template <int K_IN>
__global__ __launch_bounds__(128) void encoder_kernel(
    const float* __restrict__ x, const float* __restrict__ W0,
    const float* __restrict__ b0, const float* __restrict__ W1,
    const float* __restrict__ b1, _Float16* __restrict__ outp, int R) {
  constexpr int PIN = K_IN + 4;
  __shared__ float xs[32 * PIN];
  __shared__ float hs[32 * 132];
  const int t = threadIdx.x;
  const int r0 = blockIdx.x * 32;

  const int nvec = 32 * K_IN / 4;
  for (int i = t; i < nvec; i += 128) {
    int rr = i / (K_IN / 4);
    int kk = (i % (K_IN / 4)) * 4;
    int row = r0 + rr;
    float4 v = make_float4(0.f, 0.f, 0.f, 0.f);
    if (row < R) v = *(const float4*)&x[(size_t)row * K_IN + kk];
    *(float4*)&xs[rr * PIN + kk] = v;
  }
  __syncthreads();

  const int c0 = (t & 31) * 4;
  const int rbase = (t >> 5) * 8;
  float acc[8][4];
  {
    float4 bb = *(const float4*)&b0[c0];
#pragma unroll
    for (int r = 0; r < 8; ++r) { acc[r][0] = bb.x; acc[r][1] = bb.y; acc[r][2] = bb.z; acc[r][3] = bb.w; }
  }
  mm_block(&xs[rbase * PIN], PIN, K_IN, W0, c0, acc);
#pragma unroll
  for (int r = 0; r < 8; ++r) {
    float4 h;
    h.x = fmaxf(acc[r][0], 0.f); h.y = fmaxf(acc[r][1], 0.f);
    h.z = fmaxf(acc[r][2], 0.f); h.w = fmaxf(acc[r][3], 0.f);
    *(float4*)&hs[(rbase + r) * 132 + c0] = h;
  }
  __syncthreads();
  {
    float4 bb = *(const float4*)&b1[c0];
#pragma unroll
    for (int r = 0; r < 8; ++r) { acc[r][0] = bb.x; acc[r][1] = bb.y; acc[r][2] = bb.z; acc[r][3] = bb.w; }
  }
  mm_block(&hs[rbase * 132], 132, H, W1, c0, acc);
#pragma unroll
  for (int r = 0; r < 8; ++r) {
    int row = r0 + rbase + r;
    if (row < R) {
      f16x4 pk = {(_Float16)acc[r][0], (_Float16)acc[r][1],
                  (_Float16)acc[r][2], (_Float16)acc[r][3]};
      *(f16x4*)&outp[(size_t)row * H + c0] = pk;
    }
  }
}

// ---------------- fp32 linear (setup-time small GEMMs) ----------------
__global__ __launch_bounds__(128) void linear_kernel(
    const float* __restrict__ x, const float* __restrict__ W,
    float* __restrict__ y, int R) {
  __shared__ float xs[32 * 132];
  const int t = threadIdx.x;
  const int r0 = blockIdx.x * 32;
  {
    const int r = t & 31, q = t >> 5;
    int row = r0 + r;
    if (row >= R) row = R - 1;
    const float* src = &x[(size_t)row * H + q * 32];
#pragma unroll
    for (int j = 0; j < 8; ++j)
      *(float4*)&xs[r * 132 + q * 32 + j * 4] = *(const float4*)&src[j * 4];
  }
  __syncthreads();
  const int c0 = (t & 31) * 4;
  const int rbase = (t >> 5) * 8;
  float acc[8][4];
#pragma unroll
  for (int r = 0; r < 8; ++r) { acc[r][0] = 0.f; acc[r][1] = 0.f; acc[r][2] = 0.f; acc[r][3] = 0.f; }
  mm_block(&xs[rbase * 132], 132, H, W, c0, acc);
#pragma unroll
  for (int r = 0; r < 8; ++r) {
    int row = r0 + rbase + r;
    if (row < R)
      *(float4*)&y[(size_t)row * H + c0] =
          make_float4(acc[r][0], acc[r][1], acc[r][2], acc[r][3]);
  }
}

// bc_out[j] = sum_k v[k] * W[k*128 + j]
__global__ __launch_bounds__(128) void vecmat_kernel(
    const float* __restrict__ v, const float* __restrict__ W,
    float* __restrict__ o) {
  int j = threadIdx.x;
  float s = 0.f;
  for (int k = 0; k < H; ++k) s += v[k] * W[(size_t)k * H + j];
  o[j] = s;
}

// ---------------- prepack W[K x 128] fp32 -> MFMA B-fragment order, fp16 ----------------
// pk[((ks*8 + ct)*64 + lane)*8 + j] = W[ks*32 + (lane>>4)*8 + j][ct*16 + (lane&15)]
__global__ __launch_bounds__(64) void prepack_kernel(
    const float* __restrict__ W, _Float16* __restrict__ pk) {
  const int ks = blockIdx.x, ct = blockIdx.y, l = threadIdx.x;
  const int kbase = ks * 32 + (l >> 4) * 8;
  const int col = ct * 16 + (l & 15);
  _Float16 tmp[8];
#pragma unroll
  for (int j = 0; j < 8; ++j)
    tmp[j] = (_Float16)W[(size_t)(kbase + j) * H + col];
  *(f16x8*)&pk[((size_t)((ks * 8 + ct) * 64) + l) * 8] = *(f16x8*)tmp;
}

// ---------------- pack B2f[NN x 128] fp32 -> MFMA C-layout fp16 ----------------
// B2pk[(tile*64 + lane)*32 + ct*4 + q] = B2f[tile*16 + (lane>>4)*4 + q][ct*16 + (lane&15)]
__global__ __launch_bounds__(64) void packc_kernel(
    const float* __restrict__ B2f, _Float16* __restrict__ B2pk) {
  const int tile = blockIdx.x, l = threadIdx.x;
  const int rbase = tile * 16 + (l >> 4) * 4;
  const int col = (l & 15);
  _Float16 tmp[32];
#pragma unroll
  for (int ct = 0; ct < 8; ++ct)
#pragma unroll
    for (int q = 0; q < 4; ++q)
      tmp[ct * 4 + q] = (_Float16)B2f[(size_t)(rbase + q) * H + ct * 16 + col];
  _Float16* dst = &B2pk[((size_t)tile * 64 + l) * 32];
#pragma unroll
  for (int i = 0; i < 4; ++i)
    *(f16x8*)(dst + i * 8) = *(f16x8*)(tmp + i * 8);
}

// ---------------- counting sort by receiver ----------------
__global__ __launch_bounds__(256) void hist_kernel(const int* __restrict__ recv,
                                                   int* __restrict__ cnt) {
  int i = blockIdx.x * 256 + threadIdx.x;
  if (i < NE) atomicAdd(&cnt[recv[i]], 1);
}

__global__ __launch_bounds__(256) void scan1_kernel(const int* __restrict__ cnt,
                                                    int* __restrict__ excl,
                                                    int* __restrict__ part) {
  __shared__ int s[256];
  int t = threadIdx.x;
  int i = blockIdx.x * 256 + t;
  int v = (i < NN) ? cnt[i] : 0;
  s[t] = v;
  __syncthreads();
  for (int off = 1; off < 256; off <<= 1) {
    int x = (t >= off) ? s[t - off] : 0;
    __syncthreads();
    s[t] += x;
    __syncthreads();
  }
  if (i < NN) excl[i] = s[t] - v;
  if (t == 255) part[blockIdx.x] = s[255];
}

__global__ __launch_bounds__(256) void scan2_kernel(int* __restrict__ part, int nb) {
  __shared__ int s[256];
  int t = threadIdx.x;
  int v = (t < nb) ? part[t] : 0;
  s[t] = v;
  __syncthreads();
  for (int off = 1; off < 256; off <<= 1) {
    int x = (t >= off) ? s[t - off] : 0;
    __syncthreads();
    s[t] += x;
    __syncthreads();
  }
  if (t < nb) part[t] = s[t] - v;
}

__global__ __launch_bounds__(256) void scan3_kernel(int* __restrict__ excl,
                                                    const int* __restrict__ part,
                                                    int* __restrict__ cursor) {
  int i = blockIdx.x * 256 + threadIdx.x;
  if (i < NN) {
    int e = excl[i] + part[i >> 8];
    excl[i] = e;
    cursor[i] = e;
  }
}

__global__ __launch_bounds__(256) void scatter_kernel(
    const int* __restrict__ senders, const int* __restrict__ recv,
    int* __restrict__ cursor, int* __restrict__ sendp,
    int* __restrict__ eperm) {
  int i = blockIdx.x * 256 + threadIdx.x;
  if (i < NE) {
    int r = recv[i];
    int pos = atomicAdd(&cursor[r], 1);
    sendp[pos] = senders[i];
    eperm[pos] = i;
  }
}

// ---------------- Hs[v] = sum_{e->v} relu(edges_e @ W0 + b0), atomic-free ----------------
// Split-half waves: lanes 0-31 own edge j, lanes 32-63 own edge j+1; each lane
// computes 4 output cols; merged by shfl_xor(32) at the end. 4-edge unroll for ILP.
DEVFN void hs_accum(const float* __restrict__ x, const float (&w)[16][4],
                    const float4 bb, float4& a) {
  float4 x0 = *(const float4*)(x + 0);
  float4 x1 = *(const float4*)(x + 4);
  float4 x2 = *(const float4*)(x + 8);
  float4 x3 = *(const float4*)(x + 12);
  float h0 = bb.x, h1 = bb.y, h2 = bb.z, h3 = bb.w;
#define HS_STEP(xx, kk) \
  h0 += (xx) * w[kk][0]; h1 += (xx) * w[kk][1]; h2 += (xx) * w[kk][2]; h3 += (xx) * w[kk][3];
  HS_STEP(x0.x, 0)  HS_STEP(x0.y, 1)  HS_STEP(x0.z, 2)  HS_STEP(x0.w, 3)
  HS_STEP(x1.x, 4)  HS_STEP(x1.y, 5)  HS_STEP(x1.z, 6)  HS_STEP(x1.w, 7)
  HS_STEP(x2.x, 8)  HS_STEP(x2.y, 9)  HS_STEP(x2.z, 10) HS_STEP(x2.w, 11)
  HS_STEP(x3.x, 12) HS_STEP(x3.y, 13) HS_STEP(x3.z, 14) HS_STEP(x3.w, 15)
#undef HS_STEP
  a.x += fmaxf(h0, 0.f);
  a.y += fmaxf(h1, 0.f);
  a.z += fmaxf(h2, 0.f);
  a.w += fmaxf(h3, 0.f);
}

__global__ __launch_bounds__(256) void hs_fused_kernel(
    const float* __restrict__ edges, const int* __restrict__ eperm,
    const int* __restrict__ start, const int* __restrict__ endc,
    const float* __restrict__ W0, const float* __restrict__ b0,
    float* __restrict__ Hs) {
  const int t = threadIdx.x;
  const int v = blockIdx.x * 4 + (t >> 6);  // NN % 4 == 0
  const int lane = t & 63;
  const int half = lane >> 5;
  const int c = (lane & 31) * 4;
  float w[16][4];
#pragma unroll
  for (int k = 0; k < 16; ++k) {
    float4 ww = *(const float4*)&W0[(size_t)k * H + c];
    w[k][0] = ww.x; w[k][1] = ww.y; w[k][2] = ww.z; w[k][3] = ww.w;
  }
  const float4 bb = *(const float4*)&b0[c];
  float4 a = make_float4(0.f, 0.f, 0.f, 0.f);
  int j = start[v];
  const int e = endc[v];
  for (; j + 3 < e; j += 4) {
    int e0 = eperm[j + half];
    int e1 = eperm[j + 2 + half];
    hs_accum(&edges[(size_t)e0 * 16], w, bb, a);
    hs_accum(&edges[(size_t)e1 * 16], w, bb, a);
  }
  for (; j + 1 < e; j += 2) {
    int e0 = eperm[j + half];
    hs_accum(&edges[(size_t)e0 * 16], w, bb, a);
  }
  if (j < e && half == 0) {
    int e0 = eperm[j];
    hs_accum(&edges[(size_t)e0 * 16], w, bb, a);
  }
  a.x += __shfl_xor(a.x, 32);
  a.y += __shfl_xor(a.y, 32);
  a.z += __shfl_xor(a.z, 32);
  a.w += __shfl_xor(a.w, 32);
  if (half == 0) *(float4*)&Hs[(size_t)v * H + c] = a;
}

// ---------------- B2f[v] = Hs[v] @ Wc2 + deg[v] * bc2 ----------------
__global__ __launch_bounds__(128) void blin_kernel(
    const float* __restrict__ Hs, const float* __restrict__ Wc2,
    const float* __restrict__ bc2, const int* __restrict__ start,
    const int* __restrict__ endc, float* __restrict__ B2f) {
  __shared__ float xs[32 * 132];
  const int t = threadIdx.x;
  const int r0 = blockIdx.x * 32;
  {
    const int r = t & 31, q = t >> 5;
    int row = r0 + r;
    if (row >= NN) row = NN - 1;
    const float* src = &Hs[(size_t)row * H + q * 32];
#pragma unroll
    for (int j = 0; j < 8; ++j)
      *(float4*)&xs[r * 132 + q * 32 + j * 4] = *(const float4*)&src[j * 4];
  }
  __syncthreads();
  const int c0 = (t & 31) * 4;
  const int rbase = (t >> 5) * 8;
  const float4 bc4 = *(const float4*)&bc2[c0];
  float acc[8][4];
#pragma unroll
  for (int r = 0; r < 8; ++r) {
    int row = r0 + rbase + r;
    if (row >= NN) row = NN - 1;
    float deg = (float)(endc[row] - start[row]);
    acc[r][0] = deg * bc4.x; acc[r][1] = deg * bc4.y;
    acc[r][2] = deg * bc4.z; acc[r][3] = deg * bc4.w;
  }
  mm_block(&xs[rbase * 132], 132, H, Wc2, c0, acc);
#pragma unroll
  for (int r = 0; r < 8; ++r) {
    int row = r0 + rbase + r;
    if (row < NN)
      *(float4*)&B2f[(size_t)row * H + c0] =
          make_float4(acc[r][0], acc[r][1], acc[r][2], acc[r][3]);
  }
}

// ---------------- per-pass: S[v] = sum_{s in N(v)} n16[s]  (fp16 gather) ----------------
// Split-half waves like hs_fused; 4-edge unroll; 4 cols (8B) per lane.
__global__ __launch_bounds__(256) void gather_kernel(
    const _Float16* __restrict__ n16, const int* __restrict__ start,
    const int* __restrict__ endc, const int* __restrict__ sendp,
    _Float16* __restrict__ S) {
  const int t = threadIdx.x;
  const int v = blockIdx.x * 4 + (t >> 6);
  const int lane = t & 63;
  const int half = lane >> 5;
  const int c = (lane & 31) * 4;
  float4 a = make_float4(0.f, 0.f, 0.f, 0.f);
  int j = start[v];
  const int e = endc[v];
  for (; j + 3 < e; j += 4) {
    int s0 = sendp[j + half];
    int s1 = sendp[j + 2 + half];
    f16x4 p0 = *(const f16x4*)&n16[(size_t)s0 * H + c];
    f16x4 p1 = *(const f16x4*)&n16[(size_t)s1 * H + c];
    a.x += (float)p0[0] + (float)p1[0];
    a.y += (float)p0[1] + (float)p1[1];
    a.z += (float)p0[2] + (float)p1[2];
    a.w += (float)p0[3] + (float)p1[3];
  }
  for (; j + 1 < e; j += 2) {
    int s0 = sendp[j + half];
    f16x4 p0 = *(const f16x4*)&n16[(size_t)s0 * H + c];
    a.x += (float)p0[0]; a.y += (float)p0[1];
    a.z += (float)p0[2]; a.w += (float)p0[3];
  }
  if (j < e && half == 0) {
    int s0 = sendp[j];
    f16x4 p0 = *(const f16x4*)&n16[(size_t)s0 * H + c];
    a.x += (float)p0[0]; a.y += (float)p0[1];
    a.z += (float)p0[2]; a.w += (float)p0[3];
  }
  a.x += __shfl_xor(a.x, 32);
  a.y += __shfl_xor(a.y, 32);
  a.z += __shfl_xor(a.z, 32);
  a.w += __shfl_xor(a.w, 32);
  if (half == 0) {
    f16x4 o = {(_Float16)a.x, (_Float16)a.y, (_Float16)a.z, (_Float16)a.w};
    *(f16x4*)&S[(size_t)v * H + c] = o;
  }
}

// ---------------- MFMA node update ----------------
// pre-act = n@W0t + S@Wf + B2 + b0 ; h = relu(pre-act)
// out = LN(h@W1 + n@Wn + b1)
// 256 thr = 4 waves, 64 rows/block (16/wave). 16x16x32 f16 MFMA.
__global__ __launch_bounds__(256) void node_mfma_kernel(
    const _Float16* __restrict__ n16, const _Float16* __restrict__ S16,
    const _Float16* __restrict__ B2pk,
    const _Float16* __restrict__ pkW0t, const _Float16* __restrict__ pkWf,
    const float* __restrict__ b0,
    const _Float16* __restrict__ pkW1, const _Float16* __restrict__ pkWn,
    const float* __restrict__ b1,
    const float* __restrict__ ln_g, const float* __restrict__ ln_b,
    _Float16* __restrict__ nout) {
  __shared__ _Float16 lds[4][16 * 136];
  const int t = threadIdx.x;
  const int wave = t >> 6, lane = t & 63;
  const int row0 = blockIdx.x * 64 + wave * 16;
  const int quad = lane >> 4, m16 = lane & 15;
  _Float16* hlds = &lds[wave][0];

  int arow = row0 + m16;
  if (arow >= NN) arow = NN - 1;
  const _Float16* nrow = &n16[(size_t)arow * H + quad * 8];
  const _Float16* srow = &S16[(size_t)arow * H + quad * 8];

  // ---- C-init: b0 + B2 (prepacked C-layout) ----
  const int tile = blockIdx.x * 4 + wave;
  const _Float16* b2l = &B2pk[((size_t)tile * 64 + lane) * 32];
  f32x4 acc[8];
#pragma unroll
  for (int ct = 0; ct < 8; ++ct) {
    float bb = b0[ct * 16 + m16];
    f16x4 bv = *(const f16x4*)(b2l + ct * 4);
    acc[ct] = (f32x4){bb + (float)bv[0], bb + (float)bv[1],
                      bb + (float)bv[2], bb + (float)bv[3]};
  }
  // ---- += n @ W0t + S @ Wf ----
#pragma unroll
  for (int ks = 0; ks < 4; ++ks) {
    f16x8 an = *(const f16x8*)(nrow + ks * 32);
    f16x8 as = *(const f16x8*)(srow + ks * 32);
    const _Float16* bp0 = pkW0t + ((size_t)ks * 8 * 64 + lane) * 8;
    const _Float16* bpf = pkWf + ((size_t)ks * 8 * 64 + lane) * 8;
#pragma unroll
    for (int ct = 0; ct < 8; ++ct) {
      f16x8 bw0 = *(const f16x8*)(bp0 + ct * 512);
      acc[ct] = __builtin_amdgcn_mfma_f32_16x16x32_f16(an, bw0, acc[ct], 0, 0, 0);
      f16x8 bwf = *(const f16x8*)(bpf + ct * 512);
      acc[ct] = __builtin_amdgcn_mfma_f32_16x16x32_f16(as, bwf, acc[ct], 0, 0, 0);
    }
  }
  // relu -> wave-local LDS transpose (row-major, pitch 136)
#pragma unroll
  for (int ct = 0; ct < 8; ++ct) {
#pragma unroll
    for (int q = 0; q < 4; ++q)
      hlds[(quad * 4 + q) * 136 + ct * 16 + m16] =
          (_Float16)fmaxf(acc[ct][q], 0.f);
  }
  __syncthreads();

  // ---- acc2 = h @ W1 + b1 + n @ Wn ----
  const _Float16* hrow = &hlds[m16 * 136 + quad * 8];
  f32x4 acc2[8];
#pragma unroll
  for (int ct = 0; ct < 8; ++ct) {
    float bb = b1[ct * 16 + m16];
    acc2[ct] = (f32x4){bb, bb, bb, bb};
  }
#pragma unroll
  for (int ks = 0; ks < 4; ++ks) {
    f16x8 ah = *(const f16x8*)(hrow + ks * 32);
    f16x8 an = *(const f16x8*)(nrow + ks * 32);
    const _Float16* bp1 = pkW1 + ((size_t)ks * 8 * 64 + lane) * 8;
    const _Float16* bpn = pkWn + ((size_t)ks * 8 * 64 + lane) * 8;
#pragma unroll
    for (int ct = 0; ct < 8; ++ct) {
      f16x8 b1f = *(const f16x8*)(bp1 + ct * 512);
      acc2[ct] = __builtin_amdgcn_mfma_f32_16x16x32_f16(ah, b1f, acc2[ct], 0, 0, 0);
      f16x8 bnf = *(const f16x8*)(bpn + ct * 512);
      acc2[ct] = __builtin_amdgcn_mfma_f32_16x16x32_f16(an, bnf, acc2[ct], 0, 0, 0);
    }
  }

  // ---- LayerNorm across the 128 cols of each row ----
  float gv[8], bv[8];
#pragma unroll
  for (int ct = 0; ct < 8; ++ct) {
    gv[ct] = ln_g[ct * 16 + m16];
    bv[ct] = ln_b[ct * 16 + m16];
  }
  __syncthreads();  // all reads of hlds (h A-frags) complete before overwrite
#pragma unroll
  for (int q = 0; q < 4; ++q) {
    float s1 = 0.f, s2 = 0.f;
#pragma unroll
    for (int ct = 0; ct < 8; ++ct) {
      float v = acc2[ct][q];
      s1 += v; s2 += v * v;
    }
#pragma unroll
    for (int m = 1; m <= 8; m <<= 1) {
      s1 += __shfl_xor(s1, m);
      s2 += __shfl_xor(s2, m);
    }
    float mu = s1 * (1.f / 128.f);
    float var = s2 * (1.f / 128.f) - mu * mu;
    float rs = rsqrtf(var + LN_EPS);
#pragma unroll
    for (int ct = 0; ct < 8; ++ct) {
      float o = (acc2[ct][q] - mu) * rs * gv[ct] + bv[ct];
      hlds[(quad * 4 + q) * 136 + ct * 16 + m16] = (_Float16)o;
    }
  }
  __syncthreads();

  // linear store of LN output (fp16 row-major)
  {
    int lr = lane >> 2;
    int cc = (lane & 3) * 32;
    const _Float16* src = &hlds[lr * 136 + cc];
    int orow = row0 + lr;
    if (orow < NN) {
      _Float16* dst = &nout[(size_t)orow * H + cc];
      *(f16x8*)(dst + 0)  = *(const f16x8*)(src + 0);
      *(f16x8*)(dst + 8)  = *(const f16x8*)(src + 8);
      *(f16x8*)(dst + 16) = *(const f16x8*)(src + 16);
      *(f16x8*)(dst + 24) = *(const f16x8*)(src + 24);
    }
  }
}

// ---------------- decoder (fp16 node input) ----------------
__global__ __launch_bounds__(128) void decode_kernel(
    const _Float16* __restrict__ n, const float* __restrict__ W0,
    const float* __restrict__ b0, const float* __restrict__ W1,
    const float* __restrict__ b1, float* __restrict__ out) {
  __shared__ float xs[32 * 132];
  __shared__ float hs[32 * 132];
  const int t = threadIdx.x;
  const int r0 = blockIdx.x * 32;
  {
    const int r = t & 31, q = t >> 5;
    int row = r0 + r;
    if (row >= NN) row = NN - 1;
    const _Float16* src = &n[(size_t)row * H + q * 32];
#pragma unroll
    for (int j = 0; j < 4; ++j) {
      f16x8 v8 = *(const f16x8*)&src[j * 8];
#pragma unroll
      for (int i = 0; i < 8; ++i)
        xs[r * 132 + q * 32 + j * 8 + i] = (float)v8[i];
    }
  }
  __syncthreads();
  const int c0 = (t & 31) * 4;
  const int rbase = (t >> 5) * 8;
  float acc[8][4];
  {
    float4 bb = *(const float4*)&b0[c0];
#pragma unroll
    for (int r = 0; r < 8; ++r) { acc[r][0] = bb.x; acc[r][1] = bb.y; acc[r][2] = bb.z; acc[r][3] = bb.w; }
  }
  mm_block(&xs[rbase * 132], 132, H, W0, c0, acc);
#pragma unroll
  for (int r = 0; r < 8; ++r) {
    float4 h;
    h.x = fmaxf(acc[r][0], 0.f); h.y = fmaxf(acc[r][1], 0.f);
    h.z = fmaxf(acc[r][2], 0.f); h.w = fmaxf(acc[r][3], 0.f);
    *(float4*)&hs[(rbase + r) * 132 + c0] = h;
  }
  __syncthreads();
  if (t < 64) {
    int r = t >> 1, c = t & 1;
    float s = b1[c];
    for (int k = 0; k < H; ++k) s += hs[r * 132 + k] * W1[k * 2 + c];
    int row = r0 + r;
    if (row < NN) out[(size_t)row * 2 + c] = s;
  }
}

__global__ __launch_bounds__(256) void zero_kernel(float4* __restrict__ p, int n4) {
  int i = blockIdx.x * 256 + threadIdx.x;
  if (i < n4) p[i] = make_float4(0.f, 0.f, 0.f, 0.f);
}

}  // namespace

extern "C" void kernel_launch(void* const* d_in, const int* in_sizes, int n_in,
                              void* d_out, int out_size, void* d_ws, size_t ws_size,
                              hipStream_t stream) {
  const float* nodes     = (const float*)d_in[0];
  const float* edges     = (const float*)d_in[1];
  const int*   senders   = (const int*)d_in[2];
  const int*   receivers = (const int*)d_in[3];
  const float* enc_n_W0 = (const float*)d_in[4];
  const float* enc_n_b0 = (const float*)d_in[5];
  const float* enc_n_W1 = (const float*)d_in[6];
  const float* enc_n_b1 = (const float*)d_in[7];
  const float* enc_e_W0 = (const float*)d_in[8];
  const float* enc_e_b0 = (const float*)d_in[9];
  const float* enc_e_W1 = (const float*)d_in[10];
  const float* enc_e_b1 = (const float*)d_in[11];
  const float* W_msg    = (const float*)d_in[12];
  const float* node_W0  = (const float*)d_in[13];
  const float* node_b0  = (const float*)d_in[14];
  const float* node_W1  = (const float*)d_in[15];
  const float* node_b1  = (const float*)d_in[16];
  const float* W_node   = (const float*)d_in[17];
  const float* ln_g     = (const float*)d_in[18];
  const float* ln_b     = (const float*)d_in[19];
  const float* dec_W0   = (const float*)d_in[20];
  const float* dec_b0   = (const float*)d_in[21];
  const float* dec_W1   = (const float*)d_in[22];
  const float* dec_b1   = (const float*)d_in[23];
  float* out = (float*)d_out;

  const float* Wt  = W_msg;                // rows 0..127 of W_msg
  const float* Wb  = W_msg + 128 * H;      // rows 128..255
  const float* W0t = node_W0;              // rows 0..127 of node_W0
  const float* W0b = node_W0 + 128 * H;    // rows 128..255

  const int mfmaBlocks = (NN + 63) / 64;   // 782
  const int nTiles     = mfmaBlocks * 4;   // 3128 (packed C-tiles incl. padding)

  // workspace layout
  float* Hs   = (float*)d_ws;                          // NN*H f32
  float* B2f  = Hs + (size_t)NN * H;                   // NN*H f32
  float* Wc   = B2f + (size_t)NN * H;                  // 128*128 f32
  float* Wc2  = Wc + 128 * H;
  float* Wf32 = Wc2 + 128 * H;
  float* bc   = Wf32 + 128 * H;                        // 128
  float* bc2  = bc + 128;                              // 128
  _Float16* n16a  = (_Float16*)(bc2 + 128);            // NN*H f16
  _Float16* n16b  = n16a + (size_t)NN * H;
  _Float16* S16   = n16b + (size_t)NN * H;
  _Float16* B2pk  = S16 + (size_t)NN * H;              // nTiles*64*32 f16
  _Float16* pkW0t = B2pk + (size_t)nTiles * 64 * 32;   // 128*128 f16 each
  _Float16* pkWf  = pkW0t + 128 * H;
  _Float16* pkW1  = pkWf + 128 * H;
  _Float16* pkWn  = pkW1 + 128 * H;
  int* cnt    = (int*)(pkWn + 128 * H);
  int* excl   = cnt + NN;
  int* cursor = excl + NN;
  int* part   = cursor + NN;               // 256
  int* sendp  = part + 256;                // NE
  int* eperm  = sendp + NE;                // NE

  const int nodeBlocks = (NN + 31) / 32;     // 1563
  const int scanBlocks = (NN + 255) / 256;   // 196
  const int neBlocks   = (NE + 255) / 256;   // 2344

  // --- one-time: sort edges by receiver ---
  zero_kernel<<<(NN / 4 + 255) / 256, 256, 0, stream>>>((float4*)cnt, NN / 4);
  hist_kernel<<<neBlocks, 256, 0, stream>>>(receivers, cnt);
  scan1_kernel<<<scanBlocks, 256, 0, stream>>>(cnt, excl, part);
  scan2_kernel<<<1, 256, 0, stream>>>(part, scanBlocks);
  scan3_kernel<<<scanBlocks, 256, 0, stream>>>(excl, part, cursor);
  scatter_kernel<<<neBlocks, 256, 0, stream>>>(senders, receivers, cursor, sendp, eperm);

  // --- fold chains:  Wc = W1e@Wb;  Wc2 = Wc@W0b;  Wf = Wt@W0b;  bc2 = (b1e@Wb)@W0b ---
  linear_kernel<<<4, 128, 0, stream>>>(enc_e_W1, Wb, Wc, 128);
  vecmat_kernel<<<1, 128, 0, stream>>>(enc_e_b1, Wb, bc);
  linear_kernel<<<4, 128, 0, stream>>>(Wc, W0b, Wc2, 128);
  vecmat_kernel<<<1, 128, 0, stream>>>(bc, W0b, bc2);
  linear_kernel<<<4, 128, 0, stream>>>(Wt, W0b, Wf32, 128);
  prepack_kernel<<<dim3(4, 8), 64, 0, stream>>>(W0t, pkW0t);
  prepack_kernel<<<dim3(4, 8), 64, 0, stream>>>(Wf32, pkWf);
  prepack_kernel<<<dim3(4, 8), 64, 0, stream>>>(node_W1, pkW1);
  prepack_kernel<<<dim3(4, 8), 64, 0, stream>>>(W_node, pkWn);

  encoder_kernel<32><<<nodeBlocks, 128, 0, stream>>>(
      nodes, enc_n_W0, enc_n_b0, enc_n_W1, enc_n_b1, n16a, NN);
  hs_fused_kernel<<<NN / 4, 256, 0, stream>>>(
      edges, eperm, excl, cursor, enc_e_W0, enc_e_b0, Hs);
  blin_kernel<<<nodeBlocks, 128, 0, stream>>>(Hs, Wc2, bc2, excl, cursor, B2f);
  packc_kernel<<<NN / 16, 64, 0, stream>>>(B2f, B2pk);

  // --- 5 weight-tied passes ---
  _Float16* ncur = n16a;
  _Float16* nnxt = n16b;
  for (int p = 0; p < 5; ++p) {
    gather_kernel<<<NN / 4, 256, 0, stream>>>(ncur, excl, cursor, sendp, S16);
    node_mfma_kernel<<<mfmaBlocks, 256, 0, stream>>>(
        ncur, S16, B2pk, pkW0t, pkWf, node_b0, pkW1, pkWn, node_b1,
        ln_g, ln_b, nnxt);
    _Float16* tmp = ncur; ncur = nnxt; nnxt = tmp;
  }

  decode_kernel<<<nodeBlocks, 128, 0, stream>>>(ncur, dec_W0, dec_b0, dec_W1, dec_b1, out);
}